// Round 5
// baseline (1089.107 us; speedup 1.0000x reference)
//
#include <hip/hip_runtime.h>
#include <hip/hip_bf16.h>
#include <math.h>

#define N_NODES 50000
#define N_EDGES 800000
#define NLAYERS 8
#define ALPHA_C 0.1f
#define BN_EPS  1e-5f

typedef unsigned short u16;
typedef __attribute__((ext_vector_type(8))) short short8;
typedef __attribute__((ext_vector_type(4))) float f32x4;

static __device__ __forceinline__ u16 f2bf(float f) {
    unsigned u = __float_as_uint(f);
    unsigned r = (u + 0x7fffu + ((u >> 16) & 1u)) >> 16;
    return (u16)r;
}
static __device__ __forceinline__ float bf2f(u16 b) {
    return __uint_as_float((unsigned)b << 16);
}
static __device__ __forceinline__ float blo(unsigned w) { return __uint_as_float(w << 16); }
static __device__ __forceinline__ float bhi(unsigned w) { return __uint_as_float(w & 0xffff0000u); }

// ---------------------------------------------------------------------------
// CSR build + degree-sorted permutation
// ---------------------------------------------------------------------------
__global__ __launch_bounds__(256) void k_init(int* cnt, int* fill, float* stats, int* bins, int* binfill) {
    int i = blockIdx.x * 256 + threadIdx.x;
    if (i < N_NODES) { cnt[i] = 0; fill[i] = 0; }
    if (i < NLAYERS * 256) stats[i] = 0.0f;
    if (i < 64) { bins[i] = 0; binfill[i] = 0; }
}

__global__ __launch_bounds__(256) void k_count(const int* __restrict__ dst, int* cnt) {
    int e = blockIdx.x * 256 + threadIdx.x;
    if (e < N_EDGES) atomicAdd(&cnt[dst[e]], 1);
}

__global__ __launch_bounds__(256) void k_dinv(const int* __restrict__ cnt, float* __restrict__ dinv) {
    int i = blockIdx.x * 256 + threadIdx.x;
    if (i < N_NODES) dinv[i] = rsqrtf((float)(cnt[i] + 1));  // +1 self-loop
}

__global__ __launch_bounds__(256) void k_bin(const int* __restrict__ cnt, int* bins) {
    __shared__ int h[64];
    if (threadIdx.x < 64) h[threadIdx.x] = 0;
    __syncthreads();
    int i = blockIdx.x * 256 + threadIdx.x;
    if (i < N_NODES) atomicAdd(&h[min(cnt[i], 63)], 1);
    __syncthreads();
    if (threadIdx.x < 64 && h[threadIdx.x]) atomicAdd(&bins[threadIdx.x], h[threadIdx.x]);
}

__global__ void k_binscan(int* bins) {  // 1 block, 64 threads, exclusive in-place
    __shared__ int tmp[64];
    int t = threadIdx.x;
    int v = bins[t];
    tmp[t] = v;
    __syncthreads();
    for (int off = 1; off < 64; off <<= 1) {
        int y = (t >= off) ? tmp[t - off] : 0;
        __syncthreads();
        tmp[t] += y;
        __syncthreads();
    }
    bins[t] = tmp[t] - v;
}

__global__ __launch_bounds__(256) void k_perm(const int* __restrict__ cnt, const int* __restrict__ binoff,
                                              int* binfill, int* __restrict__ perm) {
    int i = blockIdx.x * 256 + threadIdx.x;
    if (i < N_NODES) {
        int b = min(cnt[i], 63);
        int pos = binoff[b] + atomicAdd(&binfill[b], 1);
        perm[pos] = i;
    }
}

__global__ __launch_bounds__(1024) void k_scan_local(const int* __restrict__ cnt,
                                                     int* __restrict__ rowptr, int* __restrict__ bsum) {
    __shared__ int tmp[1024];
    int t = threadIdx.x;
    int i = blockIdx.x * 1024 + t;
    int v = (i < N_NODES) ? cnt[i] : 0;
    tmp[t] = v;
    __syncthreads();
    for (int off = 1; off < 1024; off <<= 1) {
        int y = (t >= off) ? tmp[t - off] : 0;
        __syncthreads();
        tmp[t] += y;
        __syncthreads();
    }
    if (i < N_NODES) rowptr[i] = tmp[t] - v;
    if (t == 1023) bsum[blockIdx.x] = tmp[t];
}

__global__ void k_scan_top(int* bsum) {
    __shared__ int tmp[64];
    int t = threadIdx.x;
    int v = (t < 49) ? bsum[t] : 0;
    tmp[t] = v;
    __syncthreads();
    for (int off = 1; off < 64; off <<= 1) {
        int y = (t >= off) ? tmp[t - off] : 0;
        __syncthreads();
        tmp[t] += y;
        __syncthreads();
    }
    if (t < 49) bsum[t] = tmp[t] - v;
}

__global__ __launch_bounds__(256) void k_scan_add(int* __restrict__ rowptr, const int* __restrict__ bsum) {
    int i = blockIdx.x * 256 + threadIdx.x;
    if (i < N_NODES) rowptr[i] += bsum[i >> 10];
    if (i == 0) rowptr[N_NODES] = N_EDGES;
}

__global__ __launch_bounds__(256) void k_scatter(const int* __restrict__ src, const int* __restrict__ dst,
                                                 const int* __restrict__ rowptr, int* fill,
                                                 u16* __restrict__ ssrc) {
    int e = blockIdx.x * 256 + threadIdx.x;
    if (e < N_EDGES) {
        int d = dst[e];
        int pos = rowptr[d] + atomicAdd(&fill[d], 1);
        ssrc[pos] = (u16)src[e];
    }
}

// ---------------------------------------------------------------------------
// Weight convert: fp32 -> bf16, [j][k], XOR-swizzled (k' = k ^ ((j&7)<<3))
// ---------------------------------------------------------------------------
__global__ __launch_bounds__(256) void k_convw(const float* __restrict__ conv_w,
                                               const float* __restrict__ lin0_w,
                                               const float* __restrict__ lin1_w,
                                               u16* __restrict__ wtb) {
    int t = blockIdx.x * 256 + threadIdx.x;
    if (t < 131072) {                       // conv: B[j][k] = conv_w[i][k][j]
        int j = (t >> 7) & 127, k = t & 127;
        int i = t >> 14;
        float v = conv_w[(i << 14) + (k << 7) + j];
        wtb[(t & ~127) | (k ^ ((j & 7) << 3))] = f2bf(v);
    } else if (t < 131072 + 16384) {        // lin0_w [128][128] already [j][k]
        int u = t - 131072;
        int j = u >> 7, k = u & 127;
        wtb[131072 + ((u & ~127) | (k ^ ((j & 7) << 3)))] = f2bf(lin0_w[u]);
    } else if (t < 131072 + 16384 + 8192) { // lin1_w [64][128]
        int u = t - 147456;
        int j = u >> 7, k = u & 127;
        wtb[147456 + ((u & ~127) | (k ^ ((j & 7) << 3)))] = f2bf(lin1_w[u]);
    }
}

// x (fp32 row-major) -> bf16 slice-major: xb[((j>>4)*N + row)*16 + (j&15)]
__global__ __launch_bounds__(256) void k_convx(const float* __restrict__ x, u16* __restrict__ xb) {
    size_t i = ((size_t)blockIdx.x * 256 + threadIdx.x) * 4;
    int row = (int)(i >> 7), j = (int)(i & 127);
    float4 v = *(const float4*)(x + i);
    uint2 o;
    o.x = (unsigned)f2bf(v.x) | ((unsigned)f2bf(v.y) << 16);
    o.y = (unsigned)f2bf(v.z) | ((unsigned)f2bf(v.w) << 16);
    *(uint2*)(xb + ((size_t)(j >> 4) * N_NODES + row) * 16 + (j & 15)) = o;
}

// ---------------------------------------------------------------------------
// MFMA GEMM: 64 rows/block, 4 waves, K=128. A bf16 slice-major, W [j][k] swz.
// MODE 0: v=relu(acc+bias); h0b=bf16(v); hbp=bf16(v*dinv)        (slice-major)
// MODE 1: v=(1-beta)*bf2f(A) + beta*acc; Zf=v (f32 slice-major); BN stats atomics
// MODE 2: outF[row*64+j] = acc/dinv[row] + bias[j]               (row-major)
// ---------------------------------------------------------------------------
template<int NT, int MODE>
__global__ __launch_bounds__(256) void k_gemm_mfma(const u16* __restrict__ A,
                                                   const u16* __restrict__ Wg,
                                                   const float* __restrict__ bias,
                                                   float* __restrict__ Zf,
                                                   u16* __restrict__ h0b,
                                                   u16* __restrict__ hbp,
                                                   float* __restrict__ outF,
                                                   float* __restrict__ stats,
                                                   const float* __restrict__ dinv,
                                                   float beta_c, int M) {
    __shared__ u16 Ws[NT * 16 * 128];
    __shared__ float sstat[256];
    int tid = threadIdx.x;

    {
        const float4* srcv = (const float4*)Wg;
        float4* dstv = (float4*)Ws;
#pragma unroll
        for (int i = 0; i < NT; ++i) dstv[tid + i * 256] = srcv[tid + i * 256];
    }
    if (MODE == 1) sstat[tid] = 0.f;

    int wave = tid >> 6, lane = tid & 63;
    int r0 = blockIdx.x * 64 + wave * 16;
    int kg = lane >> 4;
    int cl = lane & 15;

    int arow = r0 + cl;
    int acl = arow < M ? arow : M - 1;
    short8 afrag[4];
#pragma unroll
    for (int kk = 0; kk < 4; ++kk) {
        int s = kk * 2 + (kg >> 1);
        afrag[kk] = *(const short8*)(A + ((size_t)s * N_NODES + acl) * 16 + (kg & 1) * 8);
    }

    __syncthreads();

    f32x4 acc[NT];
#pragma unroll
    for (int nt = 0; nt < NT; ++nt) {
        acc[nt] = (f32x4){0.f, 0.f, 0.f, 0.f};
        int j = nt * 16 + cl;
        const u16* wrow = Ws + j * 128;
        int sw = (j & 7) << 3;
#pragma unroll
        for (int kk = 0; kk < 4; ++kk) {
            short8 b = *(const short8*)(wrow + ((kk * 32 + kg * 8) ^ sw));
            acc[nt] = __builtin_amdgcn_mfma_f32_16x16x32_bf16(afrag[kk], b, acc[nt], 0, 0, 0);
        }
    }

    int rbase = r0 + kg * 4;
    float dvr[4];
    if (MODE != 1) {
#pragma unroll
        for (int reg = 0; reg < 4; ++reg) {
            int row = rbase + reg;
            dvr[reg] = (row < M) ? dinv[row] : 1.f;
        }
    }

#pragma unroll
    for (int nt = 0; nt < NT; ++nt) {
        int j = nt * 16 + cl;
        float s = 0.f, ss = 0.f;
#pragma unroll
        for (int reg = 0; reg < 4; ++reg) {
            int row = rbase + reg;
            if (row >= M) continue;
            float v = acc[nt][reg];
            size_t idx = ((size_t)nt * N_NODES + row) * 16 + cl;
            if (MODE == 0) {
                v = fmaxf(v + bias[j], 0.f);
                h0b[idx] = f2bf(v);
                hbp[idx] = f2bf(v * dvr[reg]);
            } else if (MODE == 1) {
                float zin = bf2f(A[idx]);
                v = (1.0f - beta_c) * zin + beta_c * v;
                Zf[idx] = v;
                s += v;
                ss = fmaf(v, v, ss);
            } else {
                outF[(size_t)row * (NT * 16) + j] = v / dvr[reg] + bias[j];
            }
        }
        if (MODE == 1) {
            s  += __shfl_xor(s, 16);  s  += __shfl_xor(s, 32);
            ss += __shfl_xor(ss, 16); ss += __shfl_xor(ss, 32);
            if (kg == 0) {
                atomicAdd(&sstat[j], s);
                atomicAdd(&sstat[128 + j], ss);
            }
        }
    }
    if (MODE == 1) {
        __syncthreads();
        atomicAdd(&stats[tid], sstat[tid]);
    }
}

// ---------------------------------------------------------------------------
// Sparse aggregation v4: slice = blockIdx&7 (XCD-pinned).
// 2 lanes/row x dwordx4 (8 feats each); 32 rows/wave, 128 rows/block.
// Rows processed in degree-sorted perm order -> near-zero intra-wave skew.
// Zb[v] = bf16( 0.9*dinv[v]*(sum hbp[src] + hbp[v]) + 0.1*h0b[v] )
// ---------------------------------------------------------------------------
__global__ __launch_bounds__(256) void k_aggregate(const u16* __restrict__ hbp, const u16* __restrict__ h0b,
                                                   const int* __restrict__ rowptr, const u16* __restrict__ ssrc,
                                                   const float* __restrict__ dinv, const int* __restrict__ perm,
                                                   u16* __restrict__ Zb) {
    int slice = blockIdx.x & 7;
    int wave = threadIdx.x >> 6, lane = threadIdx.x & 63;
    int rg = lane >> 1, hf = lane & 1;
    int idx = (blockIdx.x >> 3) * 128 + wave * 32 + rg;
    if (idx >= N_NODES) return;
    int v = perm[idx];
    const u16* hs = hbp + (size_t)slice * ((size_t)N_NODES * 16);
    int beg = rowptr[v], end = rowptr[v + 1];

    float a0, a1, a2, a3, a4, a5, a6, a7;
    {   // self-loop
        uint4 u = *(const uint4*)(hs + (size_t)v * 16 + hf * 8);
        a0 = blo(u.x); a1 = bhi(u.x); a2 = blo(u.y); a3 = bhi(u.y);
        a4 = blo(u.z); a5 = bhi(u.z); a6 = blo(u.w); a7 = bhi(u.w);
    }
    int p = beg;
    for (; p + 4 <= end; p += 4) {
        int s0 = ssrc[p], s1 = ssrc[p + 1], s2 = ssrc[p + 2], s3 = ssrc[p + 3];
        uint4 u0 = *(const uint4*)(hs + (size_t)s0 * 16 + hf * 8);
        uint4 u1 = *(const uint4*)(hs + (size_t)s1 * 16 + hf * 8);
        uint4 u2 = *(const uint4*)(hs + (size_t)s2 * 16 + hf * 8);
        uint4 u3 = *(const uint4*)(hs + (size_t)s3 * 16 + hf * 8);
        a0 += blo(u0.x); a1 += bhi(u0.x); a2 += blo(u0.y); a3 += bhi(u0.y);
        a4 += blo(u0.z); a5 += bhi(u0.z); a6 += blo(u0.w); a7 += bhi(u0.w);
        a0 += blo(u1.x); a1 += bhi(u1.x); a2 += blo(u1.y); a3 += bhi(u1.y);
        a4 += blo(u1.z); a5 += bhi(u1.z); a6 += blo(u1.w); a7 += bhi(u1.w);
        a0 += blo(u2.x); a1 += bhi(u2.x); a2 += blo(u2.y); a3 += bhi(u2.y);
        a4 += blo(u2.z); a5 += bhi(u2.z); a6 += blo(u2.w); a7 += bhi(u2.w);
        a0 += blo(u3.x); a1 += bhi(u3.x); a2 += blo(u3.y); a3 += bhi(u3.y);
        a4 += blo(u3.z); a5 += bhi(u3.z); a6 += blo(u3.w); a7 += bhi(u3.w);
    }
    for (; p < end; ++p) {
        int s = ssrc[p];
        uint4 u = *(const uint4*)(hs + (size_t)s * 16 + hf * 8);
        a0 += blo(u.x); a1 += bhi(u.x); a2 += blo(u.y); a3 += bhi(u.y);
        a4 += blo(u.z); a5 += bhi(u.z); a6 += blo(u.w); a7 += bhi(u.w);
    }

    float dv = dinv[v] * (1.0f - ALPHA_C);
    size_t oidx = ((size_t)slice * N_NODES + v) * 16 + hf * 8;
    uint4 uh = *(const uint4*)(h0b + oidx);
    float z0 = dv * a0 + ALPHA_C * blo(uh.x);
    float z1 = dv * a1 + ALPHA_C * bhi(uh.x);
    float z2 = dv * a2 + ALPHA_C * blo(uh.y);
    float z3 = dv * a3 + ALPHA_C * bhi(uh.y);
    float z4 = dv * a4 + ALPHA_C * blo(uh.z);
    float z5 = dv * a5 + ALPHA_C * bhi(uh.z);
    float z6 = dv * a6 + ALPHA_C * blo(uh.w);
    float z7 = dv * a7 + ALPHA_C * bhi(uh.w);
    uint4 o;
    o.x = (unsigned)f2bf(z0) | ((unsigned)f2bf(z1) << 16);
    o.y = (unsigned)f2bf(z2) | ((unsigned)f2bf(z3) << 16);
    o.z = (unsigned)f2bf(z4) | ((unsigned)f2bf(z5) << 16);
    o.w = (unsigned)f2bf(z6) | ((unsigned)f2bf(z7) << 16);
    *(uint4*)(Zb + oidx) = o;
}

// ---------------------------------------------------------------------------
// BN finalize + apply + relu + dinv-prescale. Zf f32 slice-major -> hbp bf16.
// ---------------------------------------------------------------------------
__global__ __launch_bounds__(256) void k_bn_relu(const float* __restrict__ Zf, const float* __restrict__ stats,
                                                 const float* __restrict__ gamma, const float* __restrict__ betap,
                                                 const float* __restrict__ dinv, u16* __restrict__ hbp) {
    __shared__ float ssc[128], ssh[128];
    int t = threadIdx.x;
    if (t < 128) {
        float mean = stats[t] * (1.0f / N_NODES);
        float var = stats[128 + t] * (1.0f / N_NODES) - mean * mean;
        float istd = rsqrtf(var + BN_EPS);
        float sc = gamma[t] * istd;
        ssc[t] = sc;
        ssh[t] = betap[t] - mean * sc;
    }
    __syncthreads();
    int e4 = blockIdx.x * 256 + t;
    if (e4 >= N_NODES * 32) return;
    int slice = e4 / (N_NODES * 4);
    int rem = e4 - slice * (N_NODES * 4);
    int row = rem >> 2;
    int j0 = slice * 16 + (rem & 3) * 4;
    float dv = dinv[row];
    float4 z = *(const float4*)(Zf + (size_t)e4 * 4);
    float r0 = fmaxf(fmaf(z.x, ssc[j0 + 0], ssh[j0 + 0]), 0.f) * dv;
    float r1 = fmaxf(fmaf(z.y, ssc[j0 + 1], ssh[j0 + 1]), 0.f) * dv;
    float r2 = fmaxf(fmaf(z.z, ssc[j0 + 2], ssh[j0 + 2]), 0.f) * dv;
    float r3 = fmaxf(fmaf(z.w, ssc[j0 + 3], ssh[j0 + 3]), 0.f) * dv;
    uint2 o;
    o.x = (unsigned)f2bf(r0) | ((unsigned)f2bf(r1) << 16);
    o.y = (unsigned)f2bf(r2) | ((unsigned)f2bf(r3) << 16);
    *(uint2*)(hbp + (size_t)e4 * 4) = o;
}

// ---------------------------------------------------------------------------

extern "C" void kernel_launch(void* const* d_in, const int* in_sizes, int n_in,
                              void* d_out, int out_size, void* d_ws, size_t ws_size,
                              hipStream_t stream) {
    const float* x      = (const float*)d_in[0];
    const int*   ei     = (const int*)d_in[1];
    const float* lin0_w = (const float*)d_in[2];
    const float* lin0_b = (const float*)d_in[3];
    const float* lin1_w = (const float*)d_in[4];
    const float* lin1_b = (const float*)d_in[5];
    const float* conv_w = (const float*)d_in[6];
    const float* bn_g   = (const float*)d_in[7];
    const float* bn_b   = (const float*)d_in[8];
    const int* e_src = ei;
    const int* e_dst = ei + N_EDGES;

    char* p = (char*)d_ws;
    auto alloc = [&](size_t bytes) -> void* {
        void* r = (void*)p;
        p += (bytes + 255) & ~(size_t)255;
        return r;
    };
    int*   cnt    = (int*)alloc((size_t)N_NODES * 4);
    int*   rowptr = (int*)alloc((size_t)(N_NODES + 1) * 4);
    int*   fill   = (int*)alloc((size_t)N_NODES * 4);
    float* dinv   = (float*)alloc((size_t)N_NODES * 4);
    u16*   ssrc   = (u16*)alloc((size_t)N_EDGES * 2);
    int*   bsum   = (int*)alloc(64 * 4);
    int*   bins   = (int*)alloc(64 * 4);
    int*   binfill= (int*)alloc(64 * 4);
    int*   perm   = (int*)alloc((size_t)N_NODES * 4);
    u16*   h0b    = (u16*)alloc((size_t)N_NODES * 128 * 2);
    float* Zf     = (float*)alloc((size_t)N_NODES * 128 * 4);
    u16*   Zb     = (u16*)alloc((size_t)N_NODES * 128 * 2);
    u16*   hbp    = (u16*)alloc((size_t)N_NODES * 128 * 2);
    u16*   wtb    = (u16*)alloc((size_t)(131072 + 16384 + 8192) * 2);
    float* stats  = (float*)alloc((size_t)NLAYERS * 256 * 4);

    const int nblk = (N_NODES + 255) / 256;
    const int eblk = (N_EDGES + 255) / 256;
    const int gblk = (N_NODES + 63) / 64;          // 782
    const int vblk = N_NODES * 128 / 4 / 256;      // 6250
    const int ablk = ((N_NODES + 127) / 128) * 8;  // 3128
    const int bnblk = (N_NODES * 32 + 255) / 256;  // 6250

    // CSR + degree-sort + prep
    k_init<<<nblk, 256, 0, stream>>>(cnt, fill, stats, bins, binfill);
    k_count<<<eblk, 256, 0, stream>>>(e_dst, cnt);
    k_dinv<<<nblk, 256, 0, stream>>>(cnt, dinv);
    k_bin<<<nblk, 256, 0, stream>>>(cnt, bins);
    k_binscan<<<1, 64, 0, stream>>>(bins);
    k_perm<<<nblk, 256, 0, stream>>>(cnt, bins, binfill, perm);
    k_scan_local<<<49, 1024, 0, stream>>>(cnt, rowptr, bsum);
    k_scan_top<<<1, 64, 0, stream>>>(bsum);
    k_scan_add<<<196, 256, 0, stream>>>(rowptr, bsum);
    k_scatter<<<eblk, 256, 0, stream>>>(e_src, e_dst, rowptr, fill, ssrc);
    k_convw<<<(131072 + 16384 + 8192 + 255) / 256, 256, 0, stream>>>(conv_w, lin0_w, lin1_w, wtb);
    k_convx<<<vblk, 256, 0, stream>>>(x, Zb);

    // input projection: h0b + hbp = relu(x @ lin0_w.T + b)
    k_gemm_mfma<8, 0><<<gblk, 256, 0, stream>>>(Zb, wtb + 131072, lin0_b, nullptr, h0b, hbp, nullptr, nullptr, dinv, 0.f, N_NODES);

    for (int i = 0; i < NLAYERS; ++i) {
        k_aggregate<<<ablk, 256, 0, stream>>>(hbp, h0b, rowptr, ssrc, dinv, perm, Zb);
        float beta = (float)log(0.5 / (double)(i + 1) + 1.0);
        k_gemm_mfma<8, 1><<<gblk, 256, 0, stream>>>(Zb, wtb + (size_t)i * 16384, nullptr, Zf, nullptr, nullptr, nullptr, stats + (size_t)i * 256, nullptr, beta, N_NODES);
        k_bn_relu<<<bnblk, 256, 0, stream>>>(Zf, stats + (size_t)i * 256, bn_g + i * 128, bn_b + i * 128, dinv, hbp);
    }

    // output projection
    k_gemm_mfma<4, 2><<<gblk, 256, 0, stream>>>(hbp, wtb + 147456, lin1_b, nullptr, nullptr, nullptr, (float*)d_out, nullptr, dinv, 0.f, N_NODES);
}

// Round 6
// 850.502 us; speedup vs baseline: 1.2805x; 1.2805x over previous
//
#include <hip/hip_runtime.h>
#include <hip/hip_bf16.h>
#include <math.h>

#define N_NODES 50000
#define N_EDGES 800000
#define NLAYERS 8
#define ALPHA_C 0.1f
#define BN_EPS  1e-5f

typedef unsigned short u16;
typedef __attribute__((ext_vector_type(8))) short short8;
typedef __attribute__((ext_vector_type(4))) float f32x4;

static __device__ __forceinline__ u16 f2bf(float f) {
    unsigned u = __float_as_uint(f);
    unsigned r = (u + 0x7fffu + ((u >> 16) & 1u)) >> 16;
    return (u16)r;
}
static __device__ __forceinline__ float bf2f(u16 b) {
    return __uint_as_float((unsigned)b << 16);
}
static __device__ __forceinline__ float blo(unsigned w) { return __uint_as_float(w << 16); }
static __device__ __forceinline__ float bhi(unsigned w) { return __uint_as_float(w & 0xffff0000u); }

// ---------------------------------------------------------------------------
// CSR build + block-local degree-sorted permutation
// ---------------------------------------------------------------------------
__global__ __launch_bounds__(256) void k_init(int* cnt, int* fill, float* stats) {
    int i = blockIdx.x * 256 + threadIdx.x;
    if (i < N_NODES) { cnt[i] = 0; fill[i] = 0; }
    if (i < NLAYERS * 256) stats[i] = 0.0f;
}

__global__ __launch_bounds__(256) void k_count(const int* __restrict__ dst, int* cnt) {
    int e = blockIdx.x * 256 + threadIdx.x;
    if (e < N_EDGES) atomicAdd(&cnt[dst[e]], 1);
}

__global__ __launch_bounds__(256) void k_dinv(const int* __restrict__ cnt, float* __restrict__ dinv) {
    int i = blockIdx.x * 256 + threadIdx.x;
    if (i < N_NODES) dinv[i] = rsqrtf((float)(cnt[i] + 1));  // +1 self-loop
}

// block-local 128-row degree sort: no atomics, perm[idx] stays within +-128 of idx
__global__ __launch_bounds__(128) void k_perm_local(const int* __restrict__ cnt, int* __restrict__ perm) {
    __shared__ int keys[128];
    int t = threadIdx.x;
    int base = blockIdx.x * 128;
    int i = base + t;
    int k = (i < N_NODES) ? cnt[i] : 0x7fffffff;
    keys[t] = k;
    __syncthreads();
    if (i < N_NODES) {
        int r = 0;
#pragma unroll 8
        for (int j = 0; j < 128; ++j) {
            int kj = keys[j];
            r += (kj < k) || (kj == k && j < t);
        }
        perm[base + r] = i;
    }
}

__global__ __launch_bounds__(1024) void k_scan_local(const int* __restrict__ cnt,
                                                     int* __restrict__ rowptr, int* __restrict__ bsum) {
    __shared__ int tmp[1024];
    int t = threadIdx.x;
    int i = blockIdx.x * 1024 + t;
    int v = (i < N_NODES) ? cnt[i] : 0;
    tmp[t] = v;
    __syncthreads();
    for (int off = 1; off < 1024; off <<= 1) {
        int y = (t >= off) ? tmp[t - off] : 0;
        __syncthreads();
        tmp[t] += y;
        __syncthreads();
    }
    if (i < N_NODES) rowptr[i] = tmp[t] - v;
    if (t == 1023) bsum[blockIdx.x] = tmp[t];
}

__global__ void k_scan_top(int* bsum) {
    __shared__ int tmp[64];
    int t = threadIdx.x;
    int v = (t < 49) ? bsum[t] : 0;
    tmp[t] = v;
    __syncthreads();
    for (int off = 1; off < 64; off <<= 1) {
        int y = (t >= off) ? tmp[t - off] : 0;
        __syncthreads();
        tmp[t] += y;
        __syncthreads();
    }
    if (t < 49) bsum[t] = tmp[t] - v;
}

__global__ __launch_bounds__(256) void k_scan_add(int* __restrict__ rowptr, const int* __restrict__ bsum) {
    int i = blockIdx.x * 256 + threadIdx.x;
    if (i < N_NODES) rowptr[i] += bsum[i >> 10];
    if (i == 0) rowptr[N_NODES] = N_EDGES;
}

__global__ __launch_bounds__(256) void k_scatter(const int* __restrict__ src, const int* __restrict__ dst,
                                                 const int* __restrict__ rowptr, int* fill,
                                                 u16* __restrict__ ssrc) {
    int e = blockIdx.x * 256 + threadIdx.x;
    if (e < N_EDGES) {
        int d = dst[e];
        int pos = rowptr[d] + atomicAdd(&fill[d], 1);
        ssrc[pos] = (u16)src[e];
    }
}

// ---------------------------------------------------------------------------
// Weight convert: fp32 -> bf16, [j][k], XOR-swizzled (k' = k ^ ((j&7)<<3))
// ---------------------------------------------------------------------------
__global__ __launch_bounds__(256) void k_convw(const float* __restrict__ conv_w,
                                               const float* __restrict__ lin0_w,
                                               const float* __restrict__ lin1_w,
                                               u16* __restrict__ wtb) {
    int t = blockIdx.x * 256 + threadIdx.x;
    if (t < 131072) {                       // conv: B[j][k] = conv_w[i][k][j]
        int j = (t >> 7) & 127, k = t & 127;
        int i = t >> 14;
        float v = conv_w[(i << 14) + (k << 7) + j];
        wtb[(t & ~127) | (k ^ ((j & 7) << 3))] = f2bf(v);
    } else if (t < 131072 + 16384) {        // lin0_w [128][128] already [j][k]
        int u = t - 131072;
        int j = u >> 7, k = u & 127;
        wtb[131072 + ((u & ~127) | (k ^ ((j & 7) << 3)))] = f2bf(lin0_w[u]);
    } else if (t < 131072 + 16384 + 8192) { // lin1_w [64][128]
        int u = t - 147456;
        int j = u >> 7, k = u & 127;
        wtb[147456 + ((u & ~127) | (k ^ ((j & 7) << 3)))] = f2bf(lin1_w[u]);
    }
}

// x (fp32 row-major) -> bf16 slice-major: xb[((j>>4)*N + row)*16 + (j&15)]
__global__ __launch_bounds__(256) void k_convx(const float* __restrict__ x, u16* __restrict__ xb) {
    size_t i = ((size_t)blockIdx.x * 256 + threadIdx.x) * 4;
    int row = (int)(i >> 7), j = (int)(i & 127);
    float4 v = *(const float4*)(x + i);
    uint2 o;
    o.x = (unsigned)f2bf(v.x) | ((unsigned)f2bf(v.y) << 16);
    o.y = (unsigned)f2bf(v.z) | ((unsigned)f2bf(v.w) << 16);
    *(uint2*)(xb + ((size_t)(j >> 4) * N_NODES + row) * 16 + (j & 15)) = o;
}

// ---------------------------------------------------------------------------
// MFMA GEMM: 64 rows/block, 4 waves, K=128. A bf16 slice-major, W [j][k] swz.
// MODE 0: v=relu(acc+bias); h0b=bf16(v); hbp=bf16(v*dinv)        (slice-major)
// MODE 1: v=(1-beta)*bf2f(A) + beta*acc; Zf=v (f32 slice-major); BN stats atomics
// MODE 2: outF[row*64+j] = acc/dinv[row] + bias[j]               (row-major)
// ---------------------------------------------------------------------------
template<int NT, int MODE>
__global__ __launch_bounds__(256) void k_gemm_mfma(const u16* __restrict__ A,
                                                   const u16* __restrict__ Wg,
                                                   const float* __restrict__ bias,
                                                   float* __restrict__ Zf,
                                                   u16* __restrict__ h0b,
                                                   u16* __restrict__ hbp,
                                                   float* __restrict__ outF,
                                                   float* __restrict__ stats,
                                                   const float* __restrict__ dinv,
                                                   float beta_c, int M) {
    __shared__ u16 Ws[NT * 16 * 128];
    __shared__ float sstat[256];
    int tid = threadIdx.x;

    {
        const float4* srcv = (const float4*)Wg;
        float4* dstv = (float4*)Ws;
#pragma unroll
        for (int i = 0; i < NT; ++i) dstv[tid + i * 256] = srcv[tid + i * 256];
    }
    if (MODE == 1) sstat[tid] = 0.f;

    int wave = tid >> 6, lane = tid & 63;
    int r0 = blockIdx.x * 64 + wave * 16;
    int kg = lane >> 4;
    int cl = lane & 15;

    int arow = r0 + cl;
    int acl = arow < M ? arow : M - 1;
    short8 afrag[4];
#pragma unroll
    for (int kk = 0; kk < 4; ++kk) {
        int s = kk * 2 + (kg >> 1);
        afrag[kk] = *(const short8*)(A + ((size_t)s * N_NODES + acl) * 16 + (kg & 1) * 8);
    }

    __syncthreads();

    f32x4 acc[NT];
#pragma unroll
    for (int nt = 0; nt < NT; ++nt) {
        acc[nt] = (f32x4){0.f, 0.f, 0.f, 0.f};
        int j = nt * 16 + cl;
        const u16* wrow = Ws + j * 128;
        int sw = (j & 7) << 3;
#pragma unroll
        for (int kk = 0; kk < 4; ++kk) {
            short8 b = *(const short8*)(wrow + ((kk * 32 + kg * 8) ^ sw));
            acc[nt] = __builtin_amdgcn_mfma_f32_16x16x32_bf16(afrag[kk], b, acc[nt], 0, 0, 0);
        }
    }

    int rbase = r0 + kg * 4;
    float dvr[4];
    if (MODE != 1) {
#pragma unroll
        for (int reg = 0; reg < 4; ++reg) {
            int row = rbase + reg;
            dvr[reg] = (row < M) ? dinv[row] : 1.f;
        }
    }

#pragma unroll
    for (int nt = 0; nt < NT; ++nt) {
        int j = nt * 16 + cl;
        float s = 0.f, ss = 0.f;
#pragma unroll
        for (int reg = 0; reg < 4; ++reg) {
            int row = rbase + reg;
            if (row >= M) continue;
            float v = acc[nt][reg];
            size_t idx = ((size_t)nt * N_NODES + row) * 16 + cl;
            if (MODE == 0) {
                v = fmaxf(v + bias[j], 0.f);
                h0b[idx] = f2bf(v);
                hbp[idx] = f2bf(v * dvr[reg]);
            } else if (MODE == 1) {
                float zin = bf2f(A[idx]);
                v = (1.0f - beta_c) * zin + beta_c * v;
                Zf[idx] = v;
                s += v;
                ss = fmaf(v, v, ss);
            } else {
                outF[(size_t)row * (NT * 16) + j] = v / dvr[reg] + bias[j];
            }
        }
        if (MODE == 1) {
            s  += __shfl_xor(s, 16);  s  += __shfl_xor(s, 32);
            ss += __shfl_xor(ss, 16); ss += __shfl_xor(ss, 32);
            if (kg == 0) {
                atomicAdd(&sstat[j], s);
                atomicAdd(&sstat[128 + j], ss);
            }
        }
    }
    if (MODE == 1) {
        __syncthreads();
        atomicAdd(&stats[tid], sstat[tid]);
    }
}

// ---------------------------------------------------------------------------
// Sparse aggregation v5: slice = blockIdx&7 (XCD-pinned).
// 2 lanes/row x dwordx4 (8 feats each); 32 rows/wave, 128 rows/block.
// Rows processed in block-local degree-sorted order (perm within +-128).
// 8-way unrolled edge loop -> 8 outstanding 16B gathers per lane.
// Zb[v] = bf16( 0.9*dinv[v]*(sum hbp[src] + hbp[v]) + 0.1*h0b[v] )
// ---------------------------------------------------------------------------
__global__ __launch_bounds__(256) void k_aggregate(const u16* __restrict__ hbp, const u16* __restrict__ h0b,
                                                   const int* __restrict__ rowptr, const u16* __restrict__ ssrc,
                                                   const float* __restrict__ dinv, const int* __restrict__ perm,
                                                   u16* __restrict__ Zb) {
    int slice = blockIdx.x & 7;
    int wave = threadIdx.x >> 6, lane = threadIdx.x & 63;
    int rg = lane >> 1, hf = lane & 1;
    int idx = (blockIdx.x >> 3) * 128 + wave * 32 + rg;
    if (idx >= N_NODES) return;
    int v = perm[idx];
    const u16* hs = hbp + (size_t)slice * ((size_t)N_NODES * 16);
    int beg = rowptr[v], end = rowptr[v + 1];

    float a0, a1, a2, a3, a4, a5, a6, a7;
    {   // self-loop
        uint4 u = *(const uint4*)(hs + (size_t)v * 16 + hf * 8);
        a0 = blo(u.x); a1 = bhi(u.x); a2 = blo(u.y); a3 = bhi(u.y);
        a4 = blo(u.z); a5 = bhi(u.z); a6 = blo(u.w); a7 = bhi(u.w);
    }
    int p = beg;
    for (; p + 8 <= end; p += 8) {
        uint4 u0 = *(const uint4*)(hs + (size_t)ssrc[p + 0] * 16 + hf * 8);
        uint4 u1 = *(const uint4*)(hs + (size_t)ssrc[p + 1] * 16 + hf * 8);
        uint4 u2 = *(const uint4*)(hs + (size_t)ssrc[p + 2] * 16 + hf * 8);
        uint4 u3 = *(const uint4*)(hs + (size_t)ssrc[p + 3] * 16 + hf * 8);
        uint4 u4 = *(const uint4*)(hs + (size_t)ssrc[p + 4] * 16 + hf * 8);
        uint4 u5 = *(const uint4*)(hs + (size_t)ssrc[p + 5] * 16 + hf * 8);
        uint4 u6 = *(const uint4*)(hs + (size_t)ssrc[p + 6] * 16 + hf * 8);
        uint4 u7 = *(const uint4*)(hs + (size_t)ssrc[p + 7] * 16 + hf * 8);
        a0 += blo(u0.x); a1 += bhi(u0.x); a2 += blo(u0.y); a3 += bhi(u0.y);
        a4 += blo(u0.z); a5 += bhi(u0.z); a6 += blo(u0.w); a7 += bhi(u0.w);
        a0 += blo(u1.x); a1 += bhi(u1.x); a2 += blo(u1.y); a3 += bhi(u1.y);
        a4 += blo(u1.z); a5 += bhi(u1.z); a6 += blo(u1.w); a7 += bhi(u1.w);
        a0 += blo(u2.x); a1 += bhi(u2.x); a2 += blo(u2.y); a3 += bhi(u2.y);
        a4 += blo(u2.z); a5 += bhi(u2.z); a6 += blo(u2.w); a7 += bhi(u2.w);
        a0 += blo(u3.x); a1 += bhi(u3.x); a2 += blo(u3.y); a3 += bhi(u3.y);
        a4 += blo(u3.z); a5 += bhi(u3.z); a6 += blo(u3.w); a7 += bhi(u3.w);
        a0 += blo(u4.x); a1 += bhi(u4.x); a2 += blo(u4.y); a3 += bhi(u4.y);
        a4 += blo(u4.z); a5 += bhi(u4.z); a6 += blo(u4.w); a7 += bhi(u4.w);
        a0 += blo(u5.x); a1 += bhi(u5.x); a2 += blo(u5.y); a3 += bhi(u5.y);
        a4 += blo(u5.z); a5 += bhi(u5.z); a6 += blo(u5.w); a7 += bhi(u5.w);
        a0 += blo(u6.x); a1 += bhi(u6.x); a2 += blo(u6.y); a3 += bhi(u6.y);
        a4 += blo(u6.z); a5 += bhi(u6.z); a6 += blo(u6.w); a7 += bhi(u6.w);
        a0 += blo(u7.x); a1 += bhi(u7.x); a2 += blo(u7.y); a3 += bhi(u7.y);
        a4 += blo(u7.z); a5 += bhi(u7.z); a6 += blo(u7.w); a7 += bhi(u7.w);
    }
    for (; p < end; ++p) {
        uint4 u = *(const uint4*)(hs + (size_t)ssrc[p] * 16 + hf * 8);
        a0 += blo(u.x); a1 += bhi(u.x); a2 += blo(u.y); a3 += bhi(u.y);
        a4 += blo(u.z); a5 += bhi(u.z); a6 += blo(u.w); a7 += bhi(u.w);
    }

    float dv = dinv[v] * (1.0f - ALPHA_C);
    size_t oidx = ((size_t)slice * N_NODES + v) * 16 + hf * 8;
    uint4 uh = *(const uint4*)(h0b + oidx);
    float z0 = dv * a0 + ALPHA_C * blo(uh.x);
    float z1 = dv * a1 + ALPHA_C * bhi(uh.x);
    float z2 = dv * a2 + ALPHA_C * blo(uh.y);
    float z3 = dv * a3 + ALPHA_C * bhi(uh.y);
    float z4 = dv * a4 + ALPHA_C * blo(uh.z);
    float z5 = dv * a5 + ALPHA_C * bhi(uh.z);
    float z6 = dv * a6 + ALPHA_C * blo(uh.w);
    float z7 = dv * a7 + ALPHA_C * bhi(uh.w);
    uint4 o;
    o.x = (unsigned)f2bf(z0) | ((unsigned)f2bf(z1) << 16);
    o.y = (unsigned)f2bf(z2) | ((unsigned)f2bf(z3) << 16);
    o.z = (unsigned)f2bf(z4) | ((unsigned)f2bf(z5) << 16);
    o.w = (unsigned)f2bf(z6) | ((unsigned)f2bf(z7) << 16);
    *(uint4*)(Zb + oidx) = o;
}

// ---------------------------------------------------------------------------
// BN finalize + apply + relu + dinv-prescale. Zf f32 slice-major -> hbp bf16.
// ---------------------------------------------------------------------------
__global__ __launch_bounds__(256) void k_bn_relu(const float* __restrict__ Zf, const float* __restrict__ stats,
                                                 const float* __restrict__ gamma, const float* __restrict__ betap,
                                                 const float* __restrict__ dinv, u16* __restrict__ hbp) {
    __shared__ float ssc[128], ssh[128];
    int t = threadIdx.x;
    if (t < 128) {
        float mean = stats[t] * (1.0f / N_NODES);
        float var = stats[128 + t] * (1.0f / N_NODES) - mean * mean;
        float istd = rsqrtf(var + BN_EPS);
        float sc = gamma[t] * istd;
        ssc[t] = sc;
        ssh[t] = betap[t] - mean * sc;
    }
    __syncthreads();
    int e4 = blockIdx.x * 256 + t;
    if (e4 >= N_NODES * 32) return;
    int slice = e4 / (N_NODES * 4);
    int rem = e4 - slice * (N_NODES * 4);
    int row = rem >> 2;
    int j0 = slice * 16 + (rem & 3) * 4;
    float dv = dinv[row];
    float4 z = *(const float4*)(Zf + (size_t)e4 * 4);
    float r0 = fmaxf(fmaf(z.x, ssc[j0 + 0], ssh[j0 + 0]), 0.f) * dv;
    float r1 = fmaxf(fmaf(z.y, ssc[j0 + 1], ssh[j0 + 1]), 0.f) * dv;
    float r2 = fmaxf(fmaf(z.z, ssc[j0 + 2], ssh[j0 + 2]), 0.f) * dv;
    float r3 = fmaxf(fmaf(z.w, ssc[j0 + 3], ssh[j0 + 3]), 0.f) * dv;
    uint2 o;
    o.x = (unsigned)f2bf(r0) | ((unsigned)f2bf(r1) << 16);
    o.y = (unsigned)f2bf(r2) | ((unsigned)f2bf(r3) << 16);
    *(uint2*)(hbp + (size_t)e4 * 4) = o;
}

// ---------------------------------------------------------------------------

extern "C" void kernel_launch(void* const* d_in, const int* in_sizes, int n_in,
                              void* d_out, int out_size, void* d_ws, size_t ws_size,
                              hipStream_t stream) {
    const float* x      = (const float*)d_in[0];
    const int*   ei     = (const int*)d_in[1];
    const float* lin0_w = (const float*)d_in[2];
    const float* lin0_b = (const float*)d_in[3];
    const float* lin1_w = (const float*)d_in[4];
    const float* lin1_b = (const float*)d_in[5];
    const float* conv_w = (const float*)d_in[6];
    const float* bn_g   = (const float*)d_in[7];
    const float* bn_b   = (const float*)d_in[8];
    const int* e_src = ei;
    const int* e_dst = ei + N_EDGES;

    char* p = (char*)d_ws;
    auto alloc = [&](size_t bytes) -> void* {
        void* r = (void*)p;
        p += (bytes + 255) & ~(size_t)255;
        return r;
    };
    int*   cnt    = (int*)alloc((size_t)N_NODES * 4);
    int*   rowptr = (int*)alloc((size_t)(N_NODES + 1) * 4);
    int*   fill   = (int*)alloc((size_t)N_NODES * 4);
    float* dinv   = (float*)alloc((size_t)N_NODES * 4);
    u16*   ssrc   = (u16*)alloc((size_t)N_EDGES * 2);
    int*   bsum   = (int*)alloc(64 * 4);
    int*   perm   = (int*)alloc((size_t)N_NODES * 4);
    u16*   h0b    = (u16*)alloc((size_t)N_NODES * 128 * 2);
    float* Zf     = (float*)alloc((size_t)N_NODES * 128 * 4);
    u16*   Zb     = (u16*)alloc((size_t)N_NODES * 128 * 2);
    u16*   hbp    = (u16*)alloc((size_t)N_NODES * 128 * 2);
    u16*   wtb    = (u16*)alloc((size_t)(131072 + 16384 + 8192) * 2);
    float* stats  = (float*)alloc((size_t)NLAYERS * 256 * 4);

    const int nblk = (N_NODES + 255) / 256;
    const int eblk = (N_EDGES + 255) / 256;
    const int gblk = (N_NODES + 63) / 64;          // 782
    const int vblk = N_NODES * 128 / 4 / 256;      // 6250
    const int ablk = ((N_NODES + 127) / 128) * 8;  // 3128
    const int pblk = (N_NODES + 127) / 128;        // 391
    const int bnblk = (N_NODES * 32 + 255) / 256;  // 6250

    // CSR + local degree-sort + prep
    k_init<<<nblk, 256, 0, stream>>>(cnt, fill, stats);
    k_count<<<eblk, 256, 0, stream>>>(e_dst, cnt);
    k_dinv<<<nblk, 256, 0, stream>>>(cnt, dinv);
    k_perm_local<<<pblk, 128, 0, stream>>>(cnt, perm);
    k_scan_local<<<49, 1024, 0, stream>>>(cnt, rowptr, bsum);
    k_scan_top<<<1, 64, 0, stream>>>(bsum);
    k_scan_add<<<196, 256, 0, stream>>>(rowptr, bsum);
    k_scatter<<<eblk, 256, 0, stream>>>(e_src, e_dst, rowptr, fill, ssrc);
    k_convw<<<(131072 + 16384 + 8192 + 255) / 256, 256, 0, stream>>>(conv_w, lin0_w, lin1_w, wtb);
    k_convx<<<vblk, 256, 0, stream>>>(x, Zb);

    // input projection: h0b + hbp = relu(x @ lin0_w.T + b)
    k_gemm_mfma<8, 0><<<gblk, 256, 0, stream>>>(Zb, wtb + 131072, lin0_b, nullptr, h0b, hbp, nullptr, nullptr, dinv, 0.f, N_NODES);

    for (int i = 0; i < NLAYERS; ++i) {
        k_aggregate<<<ablk, 256, 0, stream>>>(hbp, h0b, rowptr, ssrc, dinv, perm, Zb);
        float beta = (float)log(0.5 / (double)(i + 1) + 1.0);
        k_gemm_mfma<8, 1><<<gblk, 256, 0, stream>>>(Zb, wtb + (size_t)i * 16384, nullptr, Zf, nullptr, nullptr, nullptr, stats + (size_t)i * 256, nullptr, beta, N_NODES);
        k_bn_relu<<<bnblk, 256, 0, stream>>>(Zf, stats + (size_t)i * 256, bn_g + i * 128, bn_b + i * 128, dinv, hbp);
    }

    // output projection
    k_gemm_mfma<4, 2><<<gblk, 256, 0, stream>>>(hbp, wtb + 147456, lin1_b, nullptr, nullptr, nullptr, (float*)d_out, nullptr, dinv, 0.f, N_NODES);
}

// Round 7
// 822.490 us; speedup vs baseline: 1.3242x; 1.0341x over previous
//
#include <hip/hip_runtime.h>
#include <hip/hip_bf16.h>
#include <math.h>

#define N_NODES 50000
#define NP      (N_NODES + 1)        // slice row stride (row N = zero dummy)
#define N_EDGES 800000
#define SSRC_CAP (N_EDGES + 8 * N_NODES)   // padded CSR capacity (1.2M)
#define NLAYERS 8
#define ALPHA_C 0.1f
#define BN_EPS  1e-5f

typedef unsigned short u16;
typedef __attribute__((ext_vector_type(8))) short short8;
typedef __attribute__((ext_vector_type(4))) float f32x4;

static __device__ __forceinline__ u16 f2bf(float f) {
    unsigned u = __float_as_uint(f);
    unsigned r = (u + 0x7fffu + ((u >> 16) & 1u)) >> 16;
    return (u16)r;
}
static __device__ __forceinline__ float bf2f(u16 b) {
    return __uint_as_float((unsigned)b << 16);
}
static __device__ __forceinline__ float blo(unsigned w) { return __uint_as_float(w << 16); }
static __device__ __forceinline__ float bhi(unsigned w) { return __uint_as_float(w & 0xffff0000u); }

// ---------------------------------------------------------------------------
// init: zero cnt/fill/stats + the dummy rows (row N) of hbp in all 4 slices
// ---------------------------------------------------------------------------
__global__ __launch_bounds__(256) void k_init(int* cnt, int* fill, float* stats, u16* hbp) {
    int i = blockIdx.x * 256 + threadIdx.x;
    if (i < N_NODES) { cnt[i] = 0; fill[i] = 0; }
    if (i < NLAYERS * 256) stats[i] = 0.0f;
    if (i < 128) {  // 4 slices x 32 feats of dummy row N
        int s = i >> 5, c = i & 31;
        hbp[((size_t)s * NP + N_NODES) * 32 + c] = 0;
    }
}

// ---------------------------------------------------------------------------
// fused: degree count | convw | convx | ssrc pad-fill   (independent works)
// ---------------------------------------------------------------------------
#define CB_COUNT 3125            // ceil(E/256)
#define CB_CONVW 608             // ceil(155648/256)
#define CB_CONVX 6250            // N*128/4/256
#define CB_FILL  587             // ceil(SSRC_CAP/8/256)

__global__ __launch_bounds__(256) void k_countprep(const int* __restrict__ dst, int* cnt,
                                                   const float* __restrict__ conv_w,
                                                   const float* __restrict__ lin0_w,
                                                   const float* __restrict__ lin1_w,
                                                   u16* __restrict__ wtb,
                                                   const float* __restrict__ x, u16* __restrict__ xb,
                                                   u16* __restrict__ ssrc) {
    int b = blockIdx.x;
    if (b < CB_COUNT) {
        int e = b * 256 + threadIdx.x;
        if (e < N_EDGES) atomicAdd(&cnt[dst[e]], 1);
    } else if (b < CB_COUNT + CB_CONVW) {
        int t = (b - CB_COUNT) * 256 + threadIdx.x;
        if (t < 131072) {                       // conv: B[j][k] = conv_w[i][k][j], swizzled
            int j = (t >> 7) & 127, k = t & 127;
            int i = t >> 14;
            float v = conv_w[(i << 14) + (k << 7) + j];
            wtb[(t & ~127) | (k ^ ((j & 7) << 3))] = f2bf(v);
        } else if (t < 131072 + 16384) {        // lin0_w [128][128]
            int u = t - 131072;
            int j = u >> 7, k = u & 127;
            wtb[131072 + ((u & ~127) | (k ^ ((j & 7) << 3)))] = f2bf(lin0_w[u]);
        } else if (t < 131072 + 16384 + 8192) { // lin1_w [64][128]
            int u = t - 147456;
            int j = u >> 7, k = u & 127;
            wtb[147456 + ((u & ~127) | (k ^ ((j & 7) << 3)))] = f2bf(lin1_w[u]);
        }
    } else if (b < CB_COUNT + CB_CONVW + CB_CONVX) {
        size_t i = ((size_t)(b - CB_COUNT - CB_CONVW) * 256 + threadIdx.x) * 4;
        int row = (int)(i >> 7), j = (int)(i & 127);
        float4 v = *(const float4*)(x + i);
        uint2 o;
        o.x = (unsigned)f2bf(v.x) | ((unsigned)f2bf(v.y) << 16);
        o.y = (unsigned)f2bf(v.z) | ((unsigned)f2bf(v.w) << 16);
        *(uint2*)(xb + ((size_t)(j >> 5) * NP + row) * 32 + (j & 31)) = o;
    } else {
        // fill ssrc with dummy index N (pattern 8 x u16)
        size_t q = ((size_t)(b - CB_COUNT - CB_CONVW - CB_CONVX) * 256 + threadIdx.x);
        unsigned pat = (unsigned)N_NODES | ((unsigned)N_NODES << 16);
        if (q * 8 < SSRC_CAP) {
            uint4 o = make_uint4(pat, pat, pat, pat);
            *(uint4*)(ssrc + q * 8) = o;
        }
    }
}

// ---------------------------------------------------------------------------
// fused graph pass: dinv + block-local(128) degree sort + padded-count scan
// grid 49 x 1024
// ---------------------------------------------------------------------------
__global__ __launch_bounds__(1024) void k_graphA(const int* __restrict__ cnt, float* __restrict__ dinv,
                                                 int* __restrict__ perm,
                                                 int* __restrict__ rowptr, int* __restrict__ bsum) {
    __shared__ int tmp[1024];
    int t = threadIdx.x;
    int i = blockIdx.x * 1024 + t;
    int deg = (i < N_NODES) ? cnt[i] : 0;
    if (i < N_NODES) dinv[i] = rsqrtf((float)(deg + 1));
    // --- local degree sort over 128-row groups ---
    tmp[t] = (i < N_NODES) ? deg : 0x7fffffff;
    __syncthreads();
    {
        int g = t >> 7, tl = t & 127;
        int k = tmp[t];
        int r = 0;
#pragma unroll 8
        for (int j = 0; j < 128; ++j) {
            int kj = tmp[(g << 7) + j];
            r += (kj < k) || (kj == k && j < tl);
        }
        if (i < N_NODES) perm[blockIdx.x * 1024 + (g << 7) + r] = i;
    }
    __syncthreads();
    // --- scan of padded degrees ---
    int vpad = (i < N_NODES) ? ((deg + 7) & ~7) : 0;
    tmp[t] = vpad;
    __syncthreads();
    for (int off = 1; off < 1024; off <<= 1) {
        int y = (t >= off) ? tmp[t - off] : 0;
        __syncthreads();
        tmp[t] += y;
        __syncthreads();
    }
    if (i < N_NODES) rowptr[i] = tmp[t] - vpad;
    if (t == 1023) bsum[blockIdx.x] = tmp[t];
}

__global__ void k_scan_top(int* bsum) {
    __shared__ int tmp[64];
    int t = threadIdx.x;
    int v = (t < 49) ? bsum[t] : 0;
    tmp[t] = v;
    __syncthreads();
    for (int off = 1; off < 64; off <<= 1) {
        int y = (t >= off) ? tmp[t - off] : 0;
        __syncthreads();
        tmp[t] += y;
        __syncthreads();
    }
    if (t < 49) bsum[t] = tmp[t] - v;
    if (t == 48) bsum[63] = tmp[48];  // grand total (padded)
}

__global__ __launch_bounds__(256) void k_scan_add(int* __restrict__ rowptr, const int* __restrict__ bsum) {
    int i = blockIdx.x * 256 + threadIdx.x;
    if (i < N_NODES) rowptr[i] += bsum[i >> 10];
    if (i == 0) rowptr[N_NODES] = bsum[63];
}

__global__ __launch_bounds__(256) void k_scatter(const int* __restrict__ src, const int* __restrict__ dst,
                                                 const int* __restrict__ rowptr, int* fill,
                                                 u16* __restrict__ ssrc) {
    int e = blockIdx.x * 256 + threadIdx.x;
    if (e < N_EDGES) {
        int d = dst[e];
        int pos = rowptr[d] + atomicAdd(&fill[d], 1);
        ssrc[pos] = (u16)src[e];
    }
}

// ---------------------------------------------------------------------------
// MFMA GEMM: 64 rows/block, 4 waves, K=128. A bf16 slice-major (4x32, NP
// stride), W [j][k] swizzled in wtb.
// MODE 0: v=relu(acc+bias); h0b=bf16(v); hbp=bf16(v*dinv)
// MODE 1: v=(1-beta)*bf2f(A) + beta*acc; Zf=v (f32, slice-major); BN stats
// MODE 2: outF[row*64+j] = acc/dinv[row] + bias[j]   (row-major)
// ---------------------------------------------------------------------------
template<int NT, int MODE>
__global__ __launch_bounds__(256) void k_gemm_mfma(const u16* __restrict__ A,
                                                   const u16* __restrict__ Wg,
                                                   const float* __restrict__ bias,
                                                   float* __restrict__ Zf,
                                                   u16* __restrict__ h0b,
                                                   u16* __restrict__ hbp,
                                                   float* __restrict__ outF,
                                                   float* __restrict__ stats,
                                                   const float* __restrict__ dinv,
                                                   float beta_c, int M) {
    __shared__ u16 Ws[NT * 16 * 128];
    __shared__ float sstat[256];
    int tid = threadIdx.x;

    {
        const float4* srcv = (const float4*)Wg;
        float4* dstv = (float4*)Ws;
#pragma unroll
        for (int i = 0; i < NT; ++i) dstv[tid + i * 256] = srcv[tid + i * 256];
    }
    if (MODE == 1) sstat[tid] = 0.f;

    int wave = tid >> 6, lane = tid & 63;
    int r0 = blockIdx.x * 64 + wave * 16;
    int kg = lane >> 4;
    int cl = lane & 15;

    int arow = r0 + cl;
    int acl = arow < M ? arow : M - 1;
    short8 afrag[4];
#pragma unroll
    for (int kk = 0; kk < 4; ++kk)  // k-range [kk*32, kk*32+32) = slice kk
        afrag[kk] = *(const short8*)(A + ((size_t)kk * NP + acl) * 32 + kg * 8);

    __syncthreads();

    f32x4 acc[NT];
#pragma unroll
    for (int nt = 0; nt < NT; ++nt) {
        acc[nt] = (f32x4){0.f, 0.f, 0.f, 0.f};
        int j = nt * 16 + cl;
        const u16* wrow = Ws + j * 128;
        int sw = (j & 7) << 3;
#pragma unroll
        for (int kk = 0; kk < 4; ++kk) {
            short8 b = *(const short8*)(wrow + ((kk * 32 + kg * 8) ^ sw));
            acc[nt] = __builtin_amdgcn_mfma_f32_16x16x32_bf16(afrag[kk], b, acc[nt], 0, 0, 0);
        }
    }

    int rbase = r0 + kg * 4;
    float dvr[4];
    if (MODE != 1) {
#pragma unroll
        for (int reg = 0; reg < 4; ++reg) {
            int row = rbase + reg;
            dvr[reg] = (row < M) ? dinv[row] : 1.f;
        }
    }

#pragma unroll
    for (int nt = 0; nt < NT; ++nt) {
        int j = nt * 16 + cl;
        float s = 0.f, ss = 0.f;
#pragma unroll
        for (int reg = 0; reg < 4; ++reg) {
            int row = rbase + reg;
            if (row >= M) continue;
            float v = acc[nt][reg];
            size_t idx = ((size_t)(nt >> 1) * NP + row) * 32 + (nt & 1) * 16 + cl;
            if (MODE == 0) {
                v = fmaxf(v + bias[j], 0.f);
                h0b[idx] = f2bf(v);
                hbp[idx] = f2bf(v * dvr[reg]);
            } else if (MODE == 1) {
                float zin = bf2f(A[idx]);
                v = (1.0f - beta_c) * zin + beta_c * v;
                Zf[idx] = v;
                s += v;
                ss = fmaf(v, v, ss);
            } else {
                outF[(size_t)row * (NT * 16) + j] = v / dvr[reg] + bias[j];
            }
        }
        if (MODE == 1) {
            s  += __shfl_xor(s, 16);  s  += __shfl_xor(s, 32);
            ss += __shfl_xor(ss, 16); ss += __shfl_xor(ss, 32);
            if (kg == 0) {
                atomicAdd(&sstat[j], s);
                atomicAdd(&sstat[128 + j], ss);
            }
        }
    }
    if (MODE == 1) {
        __syncthreads();
        atomicAdd(&stats[tid], sstat[tid]);
    }
}

// ---------------------------------------------------------------------------
// Sparse aggregation v6: 4 slices x 32 feats (64B rows = 1 cache line).
// slice = blockIdx&3 (pinned to XCD pair). 4 lanes/row x 16B, 16 rows/wave,
// 64 rows/block. Padded CSR: deg_pad/8 iterations of {1 uint4 index load +
// 8 gathers}, next index vector prefetched.
// ---------------------------------------------------------------------------
__global__ __launch_bounds__(256) void k_aggregate(const u16* __restrict__ hbp, const u16* __restrict__ h0b,
                                                   const int* __restrict__ rowptr, const u16* __restrict__ ssrc,
                                                   const float* __restrict__ dinv, const int* __restrict__ perm,
                                                   u16* __restrict__ Zb) {
    int slice = blockIdx.x & 3;
    int wave = threadIdx.x >> 6, lane = threadIdx.x & 63;
    int rg = lane >> 2, hf = lane & 3;
    int idx = (blockIdx.x >> 2) * 64 + wave * 16 + rg;
    if (idx >= N_NODES) return;
    int v = perm[idx];
    const u16* hs = hbp + (size_t)slice * NP * 32;
    int beg = rowptr[v];
    int nit = (rowptr[v + 1] - beg) >> 3;

    float a0, a1, a2, a3, a4, a5, a6, a7;
    {   // self-loop
        uint4 u = *(const uint4*)(hs + (size_t)v * 32 + hf * 8);
        a0 = blo(u.x); a1 = bhi(u.x); a2 = blo(u.y); a3 = bhi(u.y);
        a4 = blo(u.z); a5 = bhi(u.z); a6 = blo(u.w); a7 = bhi(u.w);
    }
    const uint4* sv = (const uint4*)(ssrc + beg);   // beg is multiple of 8
    uint4 S;
    if (nit > 0) S = sv[0];
    for (int it = 0; it < nit; ++it) {
        uint4 Sn = (it + 1 < nit) ? sv[it + 1] : S;
        int s0 = S.x & 0xffff, s1 = S.x >> 16;
        int s2 = S.y & 0xffff, s3 = S.y >> 16;
        int s4 = S.z & 0xffff, s5 = S.z >> 16;
        int s6 = S.w & 0xffff, s7 = S.w >> 16;
        uint4 u0 = *(const uint4*)(hs + (size_t)s0 * 32 + hf * 8);
        uint4 u1 = *(const uint4*)(hs + (size_t)s1 * 32 + hf * 8);
        uint4 u2 = *(const uint4*)(hs + (size_t)s2 * 32 + hf * 8);
        uint4 u3 = *(const uint4*)(hs + (size_t)s3 * 32 + hf * 8);
        uint4 u4 = *(const uint4*)(hs + (size_t)s4 * 32 + hf * 8);
        uint4 u5 = *(const uint4*)(hs + (size_t)s5 * 32 + hf * 8);
        uint4 u6 = *(const uint4*)(hs + (size_t)s6 * 32 + hf * 8);
        uint4 u7 = *(const uint4*)(hs + (size_t)s7 * 32 + hf * 8);
        a0 += blo(u0.x); a1 += bhi(u0.x); a2 += blo(u0.y); a3 += bhi(u0.y);
        a4 += blo(u0.z); a5 += bhi(u0.z); a6 += blo(u0.w); a7 += bhi(u0.w);
        a0 += blo(u1.x); a1 += bhi(u1.x); a2 += blo(u1.y); a3 += bhi(u1.y);
        a4 += blo(u1.z); a5 += bhi(u1.z); a6 += blo(u1.w); a7 += bhi(u1.w);
        a0 += blo(u2.x); a1 += bhi(u2.x); a2 += blo(u2.y); a3 += bhi(u2.y);
        a4 += blo(u2.z); a5 += bhi(u2.z); a6 += blo(u2.w); a7 += bhi(u2.w);
        a0 += blo(u3.x); a1 += bhi(u3.x); a2 += blo(u3.y); a3 += bhi(u3.y);
        a4 += blo(u3.z); a5 += bhi(u3.z); a6 += blo(u3.w); a7 += bhi(u3.w);
        a0 += blo(u4.x); a1 += bhi(u4.x); a2 += blo(u4.y); a3 += bhi(u4.y);
        a4 += blo(u4.z); a5 += bhi(u4.z); a6 += blo(u4.w); a7 += bhi(u4.w);
        a0 += blo(u5.x); a1 += bhi(u5.x); a2 += blo(u5.y); a3 += bhi(u5.y);
        a4 += blo(u5.z); a5 += bhi(u5.z); a6 += blo(u5.w); a7 += bhi(u5.w);
        a0 += blo(u6.x); a1 += bhi(u6.x); a2 += blo(u6.y); a3 += bhi(u6.y);
        a4 += blo(u6.z); a5 += bhi(u6.z); a6 += blo(u6.w); a7 += bhi(u6.w);
        a0 += blo(u7.x); a1 += bhi(u7.x); a2 += blo(u7.y); a3 += bhi(u7.y);
        a4 += blo(u7.z); a5 += bhi(u7.z); a6 += blo(u7.w); a7 += bhi(u7.w);
        S = Sn;
    }

    float dv = dinv[v] * (1.0f - ALPHA_C);
    size_t oidx = ((size_t)slice * NP + v) * 32 + hf * 8;
    uint4 uh = *(const uint4*)(h0b + oidx);
    float z0 = dv * a0 + ALPHA_C * blo(uh.x);
    float z1 = dv * a1 + ALPHA_C * bhi(uh.x);
    float z2 = dv * a2 + ALPHA_C * blo(uh.y);
    float z3 = dv * a3 + ALPHA_C * bhi(uh.y);
    float z4 = dv * a4 + ALPHA_C * blo(uh.z);
    float z5 = dv * a5 + ALPHA_C * bhi(uh.z);
    float z6 = dv * a6 + ALPHA_C * blo(uh.w);
    float z7 = dv * a7 + ALPHA_C * bhi(uh.w);
    uint4 o;
    o.x = (unsigned)f2bf(z0) | ((unsigned)f2bf(z1) << 16);
    o.y = (unsigned)f2bf(z2) | ((unsigned)f2bf(z3) << 16);
    o.z = (unsigned)f2bf(z4) | ((unsigned)f2bf(z5) << 16);
    o.w = (unsigned)f2bf(z6) | ((unsigned)f2bf(z7) << 16);
    *(uint4*)(Zb + oidx) = o;
}

// ---------------------------------------------------------------------------
// BN finalize + apply + relu + dinv-prescale. Zf f32 slice-major -> hbp bf16.
// ---------------------------------------------------------------------------
__global__ __launch_bounds__(256) void k_bn_relu(const float* __restrict__ Zf, const float* __restrict__ stats,
                                                 const float* __restrict__ gamma, const float* __restrict__ betap,
                                                 const float* __restrict__ dinv, u16* __restrict__ hbp) {
    __shared__ float ssc[128], ssh[128];
    int t = threadIdx.x;
    if (t < 128) {
        float mean = stats[t] * (1.0f / N_NODES);
        float var = stats[128 + t] * (1.0f / N_NODES) - mean * mean;
        float istd = rsqrtf(var + BN_EPS);
        float sc = gamma[t] * istd;
        ssc[t] = sc;
        ssh[t] = betap[t] - mean * sc;
    }
    __syncthreads();
    int e4 = blockIdx.x * 256 + t;      // N*32 chunks of 4 elems
    if (e4 >= N_NODES * 32) return;
    int slice = e4 / (N_NODES * 8);
    int rem = e4 - slice * (N_NODES * 8);
    int row = rem >> 3;
    int q = rem & 7;
    size_t addr = ((size_t)slice * NP + row) * 32 + q * 4;
    int j0 = slice * 32 + q * 4;
    float dv = dinv[row];
    float4 z = *(const float4*)(Zf + addr);
    float r0 = fmaxf(fmaf(z.x, ssc[j0 + 0], ssh[j0 + 0]), 0.f) * dv;
    float r1 = fmaxf(fmaf(z.y, ssc[j0 + 1], ssh[j0 + 1]), 0.f) * dv;
    float r2 = fmaxf(fmaf(z.z, ssc[j0 + 2], ssh[j0 + 2]), 0.f) * dv;
    float r3 = fmaxf(fmaf(z.w, ssc[j0 + 3], ssh[j0 + 3]), 0.f) * dv;
    uint2 o;
    o.x = (unsigned)f2bf(r0) | ((unsigned)f2bf(r1) << 16);
    o.y = (unsigned)f2bf(r2) | ((unsigned)f2bf(r3) << 16);
    *(uint2*)(hbp + addr) = o;
}

// ---------------------------------------------------------------------------

extern "C" void kernel_launch(void* const* d_in, const int* in_sizes, int n_in,
                              void* d_out, int out_size, void* d_ws, size_t ws_size,
                              hipStream_t stream) {
    const float* x      = (const float*)d_in[0];
    const int*   ei     = (const int*)d_in[1];
    const float* lin0_w = (const float*)d_in[2];
    const float* lin0_b = (const float*)d_in[3];
    const float* lin1_w = (const float*)d_in[4];
    const float* lin1_b = (const float*)d_in[5];
    const float* conv_w = (const float*)d_in[6];
    const float* bn_g   = (const float*)d_in[7];
    const float* bn_b   = (const float*)d_in[8];
    const int* e_src = ei;
    const int* e_dst = ei + N_EDGES;

    char* p = (char*)d_ws;
    auto alloc = [&](size_t bytes) -> void* {
        void* r = (void*)p;
        p += (bytes + 255) & ~(size_t)255;
        return r;
    };
    int*   cnt    = (int*)alloc((size_t)N_NODES * 4);
    int*   rowptr = (int*)alloc((size_t)(N_NODES + 1) * 4);
    int*   fill   = (int*)alloc((size_t)N_NODES * 4);
    float* dinv   = (float*)alloc((size_t)N_NODES * 4);
    u16*   ssrc   = (u16*)alloc((size_t)SSRC_CAP * 2);
    int*   bsum   = (int*)alloc(64 * 4);
    int*   perm   = (int*)alloc((size_t)N_NODES * 4);
    u16*   h0b    = (u16*)alloc((size_t)4 * NP * 32 * 2);
    float* Zf     = (float*)alloc((size_t)4 * NP * 32 * 4);
    u16*   Zb     = (u16*)alloc((size_t)4 * NP * 32 * 2);
    u16*   hbp    = (u16*)alloc((size_t)4 * NP * 32 * 2);
    u16*   wtb    = (u16*)alloc((size_t)(131072 + 16384 + 8192) * 2);
    float* stats  = (float*)alloc((size_t)NLAYERS * 256 * 4);

    const int nblk = (N_NODES + 255) / 256;
    const int eblk = (N_EDGES + 255) / 256;
    const int gblk = (N_NODES + 63) / 64;            // 782
    const int ablk = ((N_NODES + 63) / 64) * 4;      // 3128
    const int bnblk = (N_NODES * 32 + 255) / 256;    // 6250
    const int cpblk = CB_COUNT + CB_CONVW + CB_CONVX + CB_FILL;

    k_init<<<nblk, 256, 0, stream>>>(cnt, fill, stats, hbp);
    k_countprep<<<cpblk, 256, 0, stream>>>(e_dst, cnt, conv_w, lin0_w, lin1_w, wtb, x, Zb, ssrc);
    k_graphA<<<49, 1024, 0, stream>>>(cnt, dinv, perm, rowptr, bsum);
    k_scan_top<<<1, 64, 0, stream>>>(bsum);
    k_scan_add<<<196, 256, 0, stream>>>(rowptr, bsum);
    k_scatter<<<eblk, 256, 0, stream>>>(e_src, e_dst, rowptr, fill, ssrc);

    // input projection: h0b + hbp = relu(x @ lin0_w.T + b)
    k_gemm_mfma<8, 0><<<gblk, 256, 0, stream>>>(Zb, wtb + 131072, lin0_b, nullptr, h0b, hbp, nullptr, nullptr, dinv, 0.f, N_NODES);

    for (int i = 0; i < NLAYERS; ++i) {
        k_aggregate<<<ablk, 256, 0, stream>>>(hbp, h0b, rowptr, ssrc, dinv, perm, Zb);
        float beta = (float)log(0.5 / (double)(i + 1) + 1.0);
        k_gemm_mfma<8, 1><<<gblk, 256, 0, stream>>>(Zb, wtb + (size_t)i * 16384, nullptr, Zf, nullptr, nullptr, nullptr, stats + (size_t)i * 256, nullptr, beta, N_NODES);
        k_bn_relu<<<bnblk, 256, 0, stream>>>(Zf, stats + (size_t)i * 256, bn_g + i * 128, bn_b + i * 128, dinv, hbp);
    }

    // output projection
    k_gemm_mfma<4, 2><<<gblk, 256, 0, stream>>>(hbp, wtb + 147456, lin1_b, nullptr, nullptr, nullptr, (float*)d_out, nullptr, dinv, 0.f, N_NODES);
}

// Round 8
// 760.151 us; speedup vs baseline: 1.4328x; 1.0820x over previous
//
#include <hip/hip_runtime.h>
#include <hip/hip_bf16.h>
#include <math.h>

#define N_NODES 50000
#define NP      (N_NODES + 1)        // slice row stride (row N = zero dummy)
#define N_EDGES 800000
#define SSRC_CAP (N_EDGES + 8 * N_NODES)   // padded CSR capacity (1.2M)
#define NLAYERS 8
#define ALPHA_C 0.1f
#define BN_EPS  1e-5f

typedef unsigned short u16;
typedef __attribute__((ext_vector_type(8))) short short8;
typedef __attribute__((ext_vector_type(4))) float f32x4;
typedef __attribute__((ext_vector_type(2))) float f32x2;

static __device__ __forceinline__ u16 f2bf(float f) {
    unsigned u = __float_as_uint(f);
    unsigned r = (u + 0x7fffu + ((u >> 16) & 1u)) >> 16;
    return (u16)r;
}
static __device__ __forceinline__ float bf2f(u16 b) {
    return __uint_as_float((unsigned)b << 16);
}
static __device__ __forceinline__ float blo(unsigned w) { return __uint_as_float(w << 16); }
static __device__ __forceinline__ float bhi(unsigned w) { return __uint_as_float(w & 0xffff0000u); }

// ---------------------------------------------------------------------------
// init: zero cnt/fill/stats + the dummy rows (row N) of hbp in all 4 slices
// ---------------------------------------------------------------------------
__global__ __launch_bounds__(256) void k_init(int* cnt, int* fill, float* stats, u16* hbp) {
    int i = blockIdx.x * 256 + threadIdx.x;
    if (i < N_NODES) { cnt[i] = 0; fill[i] = 0; }
    if (i < NLAYERS * 256) stats[i] = 0.0f;
    if (i < 128) {  // 4 slices x 32 feats of dummy row N
        int s = i >> 5, c = i & 31;
        hbp[((size_t)s * NP + N_NODES) * 32 + c] = 0;
    }
}

// ---------------------------------------------------------------------------
// fused: degree count | convw | convx | ssrc pad-fill   (independent works)
// ---------------------------------------------------------------------------
#define CB_COUNT 3125            // ceil(E/256)
#define CB_CONVW 608             // ceil(155648/256)
#define CB_CONVX 6250            // N*128/4/256
#define CB_FILL  587             // ceil(SSRC_CAP/8/256)

__global__ __launch_bounds__(256) void k_countprep(const int* __restrict__ dst, int* cnt,
                                                   const float* __restrict__ conv_w,
                                                   const float* __restrict__ lin0_w,
                                                   const float* __restrict__ lin1_w,
                                                   u16* __restrict__ wtb,
                                                   const float* __restrict__ x, u16* __restrict__ xb,
                                                   u16* __restrict__ ssrc) {
    int b = blockIdx.x;
    if (b < CB_COUNT) {
        int e = b * 256 + threadIdx.x;
        if (e < N_EDGES) atomicAdd(&cnt[dst[e]], 1);
    } else if (b < CB_COUNT + CB_CONVW) {
        int t = (b - CB_COUNT) * 256 + threadIdx.x;
        if (t < 131072) {                       // conv: B[j][k] = conv_w[i][k][j], swizzled
            int j = (t >> 7) & 127, k = t & 127;
            int i = t >> 14;
            float v = conv_w[(i << 14) + (k << 7) + j];
            wtb[(t & ~127) | (k ^ ((j & 7) << 3))] = f2bf(v);
        } else if (t < 131072 + 16384) {        // lin0_w [128][128]
            int u = t - 131072;
            int j = u >> 7, k = u & 127;
            wtb[131072 + ((u & ~127) | (k ^ ((j & 7) << 3)))] = f2bf(lin0_w[u]);
        } else if (t < 131072 + 16384 + 8192) { // lin1_w [64][128]
            int u = t - 147456;
            int j = u >> 7, k = u & 127;
            wtb[147456 + ((u & ~127) | (k ^ ((j & 7) << 3)))] = f2bf(lin1_w[u]);
        }
    } else if (b < CB_COUNT + CB_CONVW + CB_CONVX) {
        size_t i = ((size_t)(b - CB_COUNT - CB_CONVW) * 256 + threadIdx.x) * 4;
        int row = (int)(i >> 7), j = (int)(i & 127);
        float4 v = *(const float4*)(x + i);
        uint2 o;
        o.x = (unsigned)f2bf(v.x) | ((unsigned)f2bf(v.y) << 16);
        o.y = (unsigned)f2bf(v.z) | ((unsigned)f2bf(v.w) << 16);
        *(uint2*)(xb + ((size_t)(j >> 5) * NP + row) * 32 + (j & 31)) = o;
    } else {
        // fill ssrc with dummy index N (pattern 8 x u16)
        size_t q = ((size_t)(b - CB_COUNT - CB_CONVW - CB_CONVX) * 256 + threadIdx.x);
        unsigned pat = (unsigned)N_NODES | ((unsigned)N_NODES << 16);
        if (q * 8 < SSRC_CAP) {
            uint4 o = make_uint4(pat, pat, pat, pat);
            *(uint4*)(ssrc + q * 8) = o;
        }
    }
}

// ---------------------------------------------------------------------------
// fused graph pass: dinv + block-local(128) degree sort + padded-count scan
// grid 49 x 1024
// ---------------------------------------------------------------------------
__global__ __launch_bounds__(1024) void k_graphA(const int* __restrict__ cnt, float* __restrict__ dinv,
                                                 int* __restrict__ perm,
                                                 int* __restrict__ rowptr, int* __restrict__ bsum) {
    __shared__ int tmp[1024];
    int t = threadIdx.x;
    int i = blockIdx.x * 1024 + t;
    int deg = (i < N_NODES) ? cnt[i] : 0;
    if (i < N_NODES) dinv[i] = rsqrtf((float)(deg + 1));
    // --- local degree sort over 128-row groups ---
    tmp[t] = (i < N_NODES) ? deg : 0x7fffffff;
    __syncthreads();
    {
        int g = t >> 7, tl = t & 127;
        int k = tmp[t];
        int r = 0;
#pragma unroll 8
        for (int j = 0; j < 128; ++j) {
            int kj = tmp[(g << 7) + j];
            r += (kj < k) || (kj == k && j < tl);
        }
        if (i < N_NODES) perm[blockIdx.x * 1024 + (g << 7) + r] = i;
    }
    __syncthreads();
    // --- scan of padded degrees ---
    int vpad = (i < N_NODES) ? ((deg + 7) & ~7) : 0;
    tmp[t] = vpad;
    __syncthreads();
    for (int off = 1; off < 1024; off <<= 1) {
        int y = (t >= off) ? tmp[t - off] : 0;
        __syncthreads();
        tmp[t] += y;
        __syncthreads();
    }
    if (i < N_NODES) rowptr[i] = tmp[t] - vpad;
    if (t == 1023) bsum[blockIdx.x] = tmp[t];
}

__global__ void k_scan_top(int* bsum) {
    __shared__ int tmp[64];
    int t = threadIdx.x;
    int v = (t < 49) ? bsum[t] : 0;
    tmp[t] = v;
    __syncthreads();
    for (int off = 1; off < 64; off <<= 1) {
        int y = (t >= off) ? tmp[t - off] : 0;
        __syncthreads();
        tmp[t] += y;
        __syncthreads();
    }
    if (t < 49) bsum[t] = tmp[t] - v;
    if (t == 48) bsum[63] = tmp[48];  // grand total (padded)
}

__global__ __launch_bounds__(256) void k_scan_add(int* __restrict__ rowptr, const int* __restrict__ bsum) {
    int i = blockIdx.x * 256 + threadIdx.x;
    if (i < N_NODES) rowptr[i] += bsum[i >> 10];
    if (i == 0) rowptr[N_NODES] = bsum[63];
}

__global__ __launch_bounds__(256) void k_scatter(const int* __restrict__ src, const int* __restrict__ dst,
                                                 const int* __restrict__ rowptr, int* fill,
                                                 u16* __restrict__ ssrc) {
    int e = blockIdx.x * 256 + threadIdx.x;
    if (e < N_EDGES) {
        int d = dst[e];
        int pos = rowptr[d] + atomicAdd(&fill[d], 1);
        ssrc[pos] = (u16)src[e];
    }
}

// ---------------------------------------------------------------------------
// MFMA GEMM: 64 rows/block, 4 waves, K=128. A bf16 slice-major (4x32, NP
// stride), W [j][k] swizzled in wtb.
// MODE 0: v=relu(acc+bias); h0b=bf16(v); hbp=bf16(v*dinv)
// MODE 1: v=(1-beta)*bf2f(A) + beta*acc; Zf=v (f32, slice-major); BN stats
// MODE 2: outF[row*64+j] = acc/dinv[row] + bias[j]   (row-major)
// ---------------------------------------------------------------------------
template<int NT, int MODE>
__global__ __launch_bounds__(256) void k_gemm_mfma(const u16* __restrict__ A,
                                                   const u16* __restrict__ Wg,
                                                   const float* __restrict__ bias,
                                                   float* __restrict__ Zf,
                                                   u16* __restrict__ h0b,
                                                   u16* __restrict__ hbp,
                                                   float* __restrict__ outF,
                                                   float* __restrict__ stats,
                                                   const float* __restrict__ dinv,
                                                   float beta_c, int M) {
    __shared__ u16 Ws[NT * 16 * 128];
    __shared__ float sstat[256];
    int tid = threadIdx.x;

    {
        const float4* srcv = (const float4*)Wg;
        float4* dstv = (float4*)Ws;
#pragma unroll
        for (int i = 0; i < NT; ++i) dstv[tid + i * 256] = srcv[tid + i * 256];
    }
    if (MODE == 1) sstat[tid] = 0.f;

    int wave = tid >> 6, lane = tid & 63;
    int r0 = blockIdx.x * 64 + wave * 16;
    int kg = lane >> 4;
    int cl = lane & 15;

    int arow = r0 + cl;
    int acl = arow < M ? arow : M - 1;
    short8 afrag[4];
#pragma unroll
    for (int kk = 0; kk < 4; ++kk)  // k-range [kk*32, kk*32+32) = slice kk
        afrag[kk] = *(const short8*)(A + ((size_t)kk * NP + acl) * 32 + kg * 8);

    __syncthreads();

    f32x4 acc[NT];
#pragma unroll
    for (int nt = 0; nt < NT; ++nt) {
        acc[nt] = (f32x4){0.f, 0.f, 0.f, 0.f};
        int j = nt * 16 + cl;
        const u16* wrow = Ws + j * 128;
        int sw = (j & 7) << 3;
#pragma unroll
        for (int kk = 0; kk < 4; ++kk) {
            short8 b = *(const short8*)(wrow + ((kk * 32 + kg * 8) ^ sw));
            acc[nt] = __builtin_amdgcn_mfma_f32_16x16x32_bf16(afrag[kk], b, acc[nt], 0, 0, 0);
        }
    }

    int rbase = r0 + kg * 4;
    float dvr[4];
    if (MODE != 1) {
#pragma unroll
        for (int reg = 0; reg < 4; ++reg) {
            int row = rbase + reg;
            dvr[reg] = (row < M) ? dinv[row] : 1.f;
        }
    }

#pragma unroll
    for (int nt = 0; nt < NT; ++nt) {
        int j = nt * 16 + cl;
        float s = 0.f, ss = 0.f;
#pragma unroll
        for (int reg = 0; reg < 4; ++reg) {
            int row = rbase + reg;
            if (row >= M) continue;
            float v = acc[nt][reg];
            size_t idx = ((size_t)(nt >> 1) * NP + row) * 32 + (nt & 1) * 16 + cl;
            if (MODE == 0) {
                v = fmaxf(v + bias[j], 0.f);
                h0b[idx] = f2bf(v);
                hbp[idx] = f2bf(v * dvr[reg]);
            } else if (MODE == 1) {
                float zin = bf2f(A[idx]);
                v = (1.0f - beta_c) * zin + beta_c * v;
                Zf[idx] = v;
                s += v;
                ss = fmaf(v, v, ss);
            } else {
                outF[(size_t)row * (NT * 16) + j] = v / dvr[reg] + bias[j];
            }
        }
        if (MODE == 1) {
            s  += __shfl_xor(s, 16);  s  += __shfl_xor(s, 32);
            ss += __shfl_xor(ss, 16); ss += __shfl_xor(ss, 32);
            if (kg == 0) {
                atomicAdd(&sstat[j], s);
                atomicAdd(&sstat[128 + j], ss);
            }
        }
    }
    if (MODE == 1) {
        __syncthreads();
        atomicAdd(&stats[tid], sstat[tid]);
    }
}

// ---------------------------------------------------------------------------
// Sparse aggregation v7: 4 slices x 32 feats (64B rows = 1 cache line).
// slice = blockIdx&3. 4 lanes/row x 16B, 16 rows/wave, 64 rows/block.
// Explicit 2-deep software pipeline (A/B gather banks, ~16 loads in flight
// per lane) + packed float2 accumulation (v_pk_add_f32).
// ---------------------------------------------------------------------------
#define GATH(S, D0,D1,D2,D3,D4,D5,D6,D7) \
    D0 = *(const uint4*)(hs + (size_t)(S.x & 0xffffu) * 32 + hf * 8); \
    D1 = *(const uint4*)(hs + (size_t)(S.x >> 16)     * 32 + hf * 8); \
    D2 = *(const uint4*)(hs + (size_t)(S.y & 0xffffu) * 32 + hf * 8); \
    D3 = *(const uint4*)(hs + (size_t)(S.y >> 16)     * 32 + hf * 8); \
    D4 = *(const uint4*)(hs + (size_t)(S.z & 0xffffu) * 32 + hf * 8); \
    D5 = *(const uint4*)(hs + (size_t)(S.z >> 16)     * 32 + hf * 8); \
    D6 = *(const uint4*)(hs + (size_t)(S.w & 0xffffu) * 32 + hf * 8); \
    D7 = *(const uint4*)(hs + (size_t)(S.w >> 16)     * 32 + hf * 8);

#define ACC4(U) \
    c0 += (f32x2){blo(U.x), bhi(U.x)}; \
    c1 += (f32x2){blo(U.y), bhi(U.y)}; \
    c2 += (f32x2){blo(U.z), bhi(U.z)}; \
    c3 += (f32x2){blo(U.w), bhi(U.w)};

#define ACC8(U0,U1,U2,U3,U4,U5,U6,U7) \
    ACC4(U0) ACC4(U1) ACC4(U2) ACC4(U3) ACC4(U4) ACC4(U5) ACC4(U6) ACC4(U7)

__global__ __launch_bounds__(256) void k_aggregate(const u16* __restrict__ hbp, const u16* __restrict__ h0b,
                                                   const int* __restrict__ rowptr, const u16* __restrict__ ssrc,
                                                   const float* __restrict__ dinv, const int* __restrict__ perm,
                                                   u16* __restrict__ Zb) {
    int slice = blockIdx.x & 3;
    int wave = threadIdx.x >> 6, lane = threadIdx.x & 63;
    int rg = lane >> 2, hf = lane & 3;
    int idx = (blockIdx.x >> 2) * 64 + wave * 16 + rg;
    if (idx >= N_NODES) return;
    int v = perm[idx];
    const u16* hs = hbp + (size_t)slice * NP * 32;
    int beg = rowptr[v];
    int nit = (rowptr[v + 1] - beg) >> 3;

    f32x2 c0, c1, c2, c3;
    {   // self-loop
        uint4 u = *(const uint4*)(hs + (size_t)v * 32 + hf * 8);
        c0 = (f32x2){blo(u.x), bhi(u.x)};
        c1 = (f32x2){blo(u.y), bhi(u.y)};
        c2 = (f32x2){blo(u.z), bhi(u.z)};
        c3 = (f32x2){blo(u.w), bhi(u.w)};
    }
    const uint4* sv = (const uint4*)(ssrc + beg);   // beg is multiple of 8
    if (nit > 0) {
        uint4 A0, A1, A2, A3, A4, A5, A6, A7;
        uint4 B0, B1, B2, B3, B4, B5, B6, B7;
        uint4 S = sv[0];
        GATH(S, A0, A1, A2, A3, A4, A5, A6, A7)
        int it = 0;
        for (; it + 2 <= nit; it += 2) {
            uint4 T = sv[it + 1];
            GATH(T, B0, B1, B2, B3, B4, B5, B6, B7)
            ACC8(A0, A1, A2, A3, A4, A5, A6, A7)
            if (it + 2 < nit) {
                S = sv[it + 2];
                GATH(S, A0, A1, A2, A3, A4, A5, A6, A7)
            }
            ACC8(B0, B1, B2, B3, B4, B5, B6, B7)
        }
        if (it < nit) {   // odd tail: bank A holds the last gathered vector
            ACC8(A0, A1, A2, A3, A4, A5, A6, A7)
        }
    }

    float dv = dinv[v] * (1.0f - ALPHA_C);
    size_t oidx = ((size_t)slice * NP + v) * 32 + hf * 8;
    uint4 uh = *(const uint4*)(h0b + oidx);
    f32x2 z0 = dv * c0 + ALPHA_C * (f32x2){blo(uh.x), bhi(uh.x)};
    f32x2 z1 = dv * c1 + ALPHA_C * (f32x2){blo(uh.y), bhi(uh.y)};
    f32x2 z2 = dv * c2 + ALPHA_C * (f32x2){blo(uh.z), bhi(uh.z)};
    f32x2 z3 = dv * c3 + ALPHA_C * (f32x2){blo(uh.w), bhi(uh.w)};
    uint4 o;
    o.x = (unsigned)f2bf(z0.x) | ((unsigned)f2bf(z0.y) << 16);
    o.y = (unsigned)f2bf(z1.x) | ((unsigned)f2bf(z1.y) << 16);
    o.z = (unsigned)f2bf(z2.x) | ((unsigned)f2bf(z2.y) << 16);
    o.w = (unsigned)f2bf(z3.x) | ((unsigned)f2bf(z3.y) << 16);
    *(uint4*)(Zb + oidx) = o;
}

// ---------------------------------------------------------------------------
// BN finalize + apply + relu + dinv-prescale. Zf f32 slice-major -> hbp bf16.
// 8 floats (32B) per thread.
// ---------------------------------------------------------------------------
__global__ __launch_bounds__(256) void k_bn_relu(const float* __restrict__ Zf, const float* __restrict__ stats,
                                                 const float* __restrict__ gamma, const float* __restrict__ betap,
                                                 const float* __restrict__ dinv, u16* __restrict__ hbp) {
    __shared__ float ssc[128], ssh[128];
    int t = threadIdx.x;
    if (t < 128) {
        float mean = stats[t] * (1.0f / N_NODES);
        float var = stats[128 + t] * (1.0f / N_NODES) - mean * mean;
        float istd = rsqrtf(var + BN_EPS);
        float sc = gamma[t] * istd;
        ssc[t] = sc;
        ssh[t] = betap[t] - mean * sc;
    }
    __syncthreads();
    int e8 = blockIdx.x * 256 + t;      // N*16 chunks of 8 elems
    if (e8 >= N_NODES * 16) return;
    int slice = e8 / (N_NODES * 4);
    int rem = e8 - slice * (N_NODES * 4);
    int row = rem >> 2;
    int q = rem & 3;
    size_t addr = ((size_t)slice * NP + row) * 32 + q * 8;
    int j0 = slice * 32 + q * 8;
    float dv = dinv[row];
    float4 za = *(const float4*)(Zf + addr);
    float4 zb = *(const float4*)(Zf + addr + 4);
    float r0 = fmaxf(fmaf(za.x, ssc[j0 + 0], ssh[j0 + 0]), 0.f) * dv;
    float r1 = fmaxf(fmaf(za.y, ssc[j0 + 1], ssh[j0 + 1]), 0.f) * dv;
    float r2 = fmaxf(fmaf(za.z, ssc[j0 + 2], ssh[j0 + 2]), 0.f) * dv;
    float r3 = fmaxf(fmaf(za.w, ssc[j0 + 3], ssh[j0 + 3]), 0.f) * dv;
    float r4 = fmaxf(fmaf(zb.x, ssc[j0 + 4], ssh[j0 + 4]), 0.f) * dv;
    float r5 = fmaxf(fmaf(zb.y, ssc[j0 + 5], ssh[j0 + 5]), 0.f) * dv;
    float r6 = fmaxf(fmaf(zb.z, ssc[j0 + 6], ssh[j0 + 6]), 0.f) * dv;
    float r7 = fmaxf(fmaf(zb.w, ssc[j0 + 7], ssh[j0 + 7]), 0.f) * dv;
    uint4 o;
    o.x = (unsigned)f2bf(r0) | ((unsigned)f2bf(r1) << 16);
    o.y = (unsigned)f2bf(r2) | ((unsigned)f2bf(r3) << 16);
    o.z = (unsigned)f2bf(r4) | ((unsigned)f2bf(r5) << 16);
    o.w = (unsigned)f2bf(r6) | ((unsigned)f2bf(r7) << 16);
    *(uint4*)(hbp + addr) = o;
}

// ---------------------------------------------------------------------------

extern "C" void kernel_launch(void* const* d_in, const int* in_sizes, int n_in,
                              void* d_out, int out_size, void* d_ws, size_t ws_size,
                              hipStream_t stream) {
    const float* x      = (const float*)d_in[0];
    const int*   ei     = (const int*)d_in[1];
    const float* lin0_w = (const float*)d_in[2];
    const float* lin0_b = (const float*)d_in[3];
    const float* lin1_w = (const float*)d_in[4];
    const float* lin1_b = (const float*)d_in[5];
    const float* conv_w = (const float*)d_in[6];
    const float* bn_g   = (const float*)d_in[7];
    const float* bn_b   = (const float*)d_in[8];
    const int* e_src = ei;
    const int* e_dst = ei + N_EDGES;

    char* p = (char*)d_ws;
    auto alloc = [&](size_t bytes) -> void* {
        void* r = (void*)p;
        p += (bytes + 255) & ~(size_t)255;
        return r;
    };
    int*   cnt    = (int*)alloc((size_t)N_NODES * 4);
    int*   rowptr = (int*)alloc((size_t)(N_NODES + 1) * 4);
    int*   fill   = (int*)alloc((size_t)N_NODES * 4);
    float* dinv   = (float*)alloc((size_t)N_NODES * 4);
    u16*   ssrc   = (u16*)alloc((size_t)SSRC_CAP * 2);
    int*   bsum   = (int*)alloc(64 * 4);
    int*   perm   = (int*)alloc((size_t)N_NODES * 4);
    u16*   h0b    = (u16*)alloc((size_t)4 * NP * 32 * 2);
    float* Zf     = (float*)alloc((size_t)4 * NP * 32 * 4);
    u16*   Zb     = (u16*)alloc((size_t)4 * NP * 32 * 2);
    u16*   hbp    = (u16*)alloc((size_t)4 * NP * 32 * 2);
    u16*   wtb    = (u16*)alloc((size_t)(131072 + 16384 + 8192) * 2);
    float* stats  = (float*)alloc((size_t)NLAYERS * 256 * 4);

    const int nblk = (N_NODES + 255) / 256;
    const int eblk = (N_EDGES + 255) / 256;
    const int gblk = (N_NODES + 63) / 64;            // 782
    const int ablk = ((N_NODES + 63) / 64) * 4;      // 3128
    const int bnblk = N_NODES * 16 / 256;            // 3125
    const int cpblk = CB_COUNT + CB_CONVW + CB_CONVX + CB_FILL;

    k_init<<<nblk, 256, 0, stream>>>(cnt, fill, stats, hbp);
    k_countprep<<<cpblk, 256, 0, stream>>>(e_dst, cnt, conv_w, lin0_w, lin1_w, wtb, x, Zb, ssrc);
    k_graphA<<<49, 1024, 0, stream>>>(cnt, dinv, perm, rowptr, bsum);
    k_scan_top<<<1, 64, 0, stream>>>(bsum);
    k_scan_add<<<196, 256, 0, stream>>>(rowptr, bsum);
    k_scatter<<<eblk, 256, 0, stream>>>(e_src, e_dst, rowptr, fill, ssrc);

    // input projection: h0b + hbp = relu(x @ lin0_w.T + b)
    k_gemm_mfma<8, 0><<<gblk, 256, 0, stream>>>(Zb, wtb + 131072, lin0_b, nullptr, h0b, hbp, nullptr, nullptr, dinv, 0.f, N_NODES);

    for (int i = 0; i < NLAYERS; ++i) {
        k_aggregate<<<ablk, 256, 0, stream>>>(hbp, h0b, rowptr, ssrc, dinv, perm, Zb);
        float beta = (float)log(0.5 / (double)(i + 1) + 1.0);
        k_gemm_mfma<8, 1><<<gblk, 256, 0, stream>>>(Zb, wtb + (size_t)i * 16384, nullptr, Zf, nullptr, nullptr, nullptr, stats + (size_t)i * 256, nullptr, beta, N_NODES);
        k_bn_relu<<<bnblk, 256, 0, stream>>>(Zf, stats + (size_t)i * 256, bn_g + i * 128, bn_b + i * 128, dinv, hbp);
    }

    // output projection
    k_gemm_mfma<4, 2><<<gblk, 256, 0, stream>>>(hbp, wtb + 147456, lin1_b, nullptr, nullptr, nullptr, (float*)d_out, nullptr, dinv, 0.f, N_NODES);
}

// Round 10
// 753.160 us; speedup vs baseline: 1.4461x; 1.0093x over previous
//
#include <hip/hip_runtime.h>
#include <hip/hip_bf16.h>
#include <math.h>

#define N_NODES 50000
#define NP      (N_NODES + 1)        // slice row stride (row N = zero dummy)
#define N_EDGES 800000
#define SSRC_CAP (N_EDGES + 8 * N_NODES)   // padded CSR capacity (1.2M)
#define NLAYERS 8
#define ALPHA_C 0.1f
#define BN_EPS  1e-5f

typedef unsigned short u16;
typedef __attribute__((ext_vector_type(8))) short short8;
typedef __attribute__((ext_vector_type(4))) float f32x4;
typedef __attribute__((ext_vector_type(2))) float f32x2;

static __device__ __forceinline__ u16 f2bf(float f) {
    unsigned u = __float_as_uint(f);
    unsigned r = (u + 0x7fffu + ((u >> 16) & 1u)) >> 16;
    return (u16)r;
}
static __device__ __forceinline__ float bf2f(u16 b) {
    return __uint_as_float((unsigned)b << 16);
}
static __device__ __forceinline__ float blo(unsigned w) { return __uint_as_float(w << 16); }
static __device__ __forceinline__ float bhi(unsigned w) { return __uint_as_float(w & 0xffff0000u); }

// ---------------------------------------------------------------------------
// init: zero cnt/fill/stats + the dummy rows (row N) of hbp in all 4 slices
// ---------------------------------------------------------------------------
__global__ __launch_bounds__(256) void k_init(int* cnt, int* fill, float* stats, u16* hbp) {
    int i = blockIdx.x * 256 + threadIdx.x;
    if (i < N_NODES) { cnt[i] = 0; fill[i] = 0; }
    if (i < NLAYERS * 256) stats[i] = 0.0f;
    if (i < 128) {  // 4 slices x 32 feats of dummy row N
        int s = i >> 5, c = i & 31;
        hbp[((size_t)s * NP + N_NODES) * 32 + c] = 0;
    }
}

// ---------------------------------------------------------------------------
// fused: degree count | convw | ssrc pad-fill   (independent works)
// ---------------------------------------------------------------------------
#define CB_COUNT 3125            // ceil(E/256)
#define CB_CONVW 608             // ceil(155648/256)
#define CB_FILL  587             // ceil(SSRC_CAP/8/256)

__global__ __launch_bounds__(256) void k_countprep(const int* __restrict__ dst, int* cnt,
                                                   const float* __restrict__ conv_w,
                                                   const float* __restrict__ lin0_w,
                                                   const float* __restrict__ lin1_w,
                                                   u16* __restrict__ wtb,
                                                   u16* __restrict__ ssrc) {
    int b = blockIdx.x;
    if (b < CB_COUNT) {
        int e = b * 256 + threadIdx.x;
        if (e < N_EDGES) atomicAdd(&cnt[dst[e]], 1);
    } else if (b < CB_COUNT + CB_CONVW) {
        int t = (b - CB_COUNT) * 256 + threadIdx.x;
        if (t < 131072) {                       // conv: B[j][k] = conv_w[i][k][j], swizzled
            int j = (t >> 7) & 127, k = t & 127;
            int i = t >> 14;
            float v = conv_w[(i << 14) + (k << 7) + j];
            wtb[(t & ~127) | (k ^ ((j & 7) << 3))] = f2bf(v);
        } else if (t < 131072 + 16384) {        // lin0_w [128][128]
            int u = t - 131072;
            int j = u >> 7, k = u & 127;
            wtb[131072 + ((u & ~127) | (k ^ ((j & 7) << 3)))] = f2bf(lin0_w[u]);
        } else if (t < 131072 + 16384 + 8192) { // lin1_w [64][128]
            int u = t - 147456;
            int j = u >> 7, k = u & 127;
            wtb[147456 + ((u & ~127) | (k ^ ((j & 7) << 3)))] = f2bf(lin1_w[u]);
        }
    } else {
        // fill ssrc with dummy index N (pattern 8 x u16)
        size_t q = ((size_t)(b - CB_COUNT - CB_CONVW) * 256 + threadIdx.x);
        unsigned pat = (unsigned)N_NODES | ((unsigned)N_NODES << 16);
        if (q * 8 < SSRC_CAP) {
            uint4 o = make_uint4(pat, pat, pat, pat);
            *(uint4*)(ssrc + q * 8) = o;
        }
    }
}

// ---------------------------------------------------------------------------
// fused graph pass: dinv + block-local(128) degree sort + padded-count scan
// grid 49 x 1024
// ---------------------------------------------------------------------------
__global__ __launch_bounds__(1024) void k_graphA(const int* __restrict__ cnt, float* __restrict__ dinv,
                                                 int* __restrict__ perm,
                                                 int* __restrict__ rowptr, int* __restrict__ bsum) {
    __shared__ int tmp[1024];
    int t = threadIdx.x;
    int i = blockIdx.x * 1024 + t;
    int deg = (i < N_NODES) ? cnt[i] : 0;
    if (i < N_NODES) dinv[i] = rsqrtf((float)(deg + 1));
    // --- local degree sort over 128-row groups ---
    tmp[t] = (i < N_NODES) ? deg : 0x7fffffff;
    __syncthreads();
    {
        int g = t >> 7, tl = t & 127;
        int k = tmp[t];
        int r = 0;
#pragma unroll 8
        for (int j = 0; j < 128; ++j) {
            int kj = tmp[(g << 7) + j];
            r += (kj < k) || (kj == k && j < tl);
        }
        if (i < N_NODES) perm[blockIdx.x * 1024 + (g << 7) + r] = i;
    }
    __syncthreads();
    // --- scan of padded degrees ---
    int vpad = (i < N_NODES) ? ((deg + 7) & ~7) : 0;
    tmp[t] = vpad;
    __syncthreads();
    for (int off = 1; off < 1024; off <<= 1) {
        int y = (t >= off) ? tmp[t - off] : 0;
        __syncthreads();
        tmp[t] += y;
        __syncthreads();
    }
    if (i < N_NODES) rowptr[i] = tmp[t] - vpad;
    if (t == 1023) bsum[blockIdx.x] = tmp[t];
}

__global__ void k_scan_top(int* bsum) {
    __shared__ int tmp[64];
    int t = threadIdx.x;
    int v = (t < 49) ? bsum[t] : 0;
    tmp[t] = v;
    __syncthreads();
    for (int off = 1; off < 64; off <<= 1) {
        int y = (t >= off) ? tmp[t - off] : 0;
        __syncthreads();
        tmp[t] += y;
        __syncthreads();
    }
    if (t < 49) bsum[t] = tmp[t] - v;
    if (t == 48) bsum[63] = tmp[48];  // grand total (padded)
}

__global__ __launch_bounds__(256) void k_scan_add(int* __restrict__ rowptr, const int* __restrict__ bsum) {
    int i = blockIdx.x * 256 + threadIdx.x;
    if (i < N_NODES) rowptr[i] += bsum[i >> 10];
    if (i == 0) rowptr[N_NODES] = bsum[63];
}

__global__ __launch_bounds__(256) void k_scatter(const int* __restrict__ src, const int* __restrict__ dst,
                                                 const int* __restrict__ rowptr, int* fill,
                                                 u16* __restrict__ ssrc) {
    int e = blockIdx.x * 256 + threadIdx.x;
    if (e < N_EDGES) {
        int d = dst[e];
        int pos = rowptr[d] + atomicAdd(&fill[d], 1);
        ssrc[pos] = (u16)src[e];
    }
}

// ---------------------------------------------------------------------------
// MFMA GEMM: 64 rows/block, 4 waves, K=128. W [j][k] swizzled in wtb.
// MODE 0: A from Xf (f32 row-major, converted); v=relu(acc+bias);
//         h0b=bf16(v); hbp=bf16(v*dinv)                       (slice-major)
// MODE 1: A from Zrw (bf16 slice-major); v=(1-beta)*bf2f(Zrw)+beta*acc;
//         Zrw=bf16(v) IN PLACE; BN stats atomics (f32, pre-rounding)
// MODE 2: A from Zrw (=hbp); outF[row*64+j] = acc/dinv[row] + bias[j]
// ---------------------------------------------------------------------------
template<int NT, int MODE>
__global__ __launch_bounds__(256) void k_gemm_mfma(const float* __restrict__ Xf,
                                                   u16* Zrw,
                                                   const u16* __restrict__ Wg,
                                                   const float* __restrict__ bias,
                                                   u16* __restrict__ h0b,
                                                   u16* __restrict__ hbp,
                                                   float* __restrict__ outF,
                                                   float* __restrict__ stats,
                                                   const float* __restrict__ dinv,
                                                   float beta_c, int M) {
    __shared__ u16 Ws[NT * 16 * 128];
    __shared__ float sstat[256];
    int tid = threadIdx.x;

    {
        const float4* srcv = (const float4*)Wg;
        float4* dstv = (float4*)Ws;
#pragma unroll
        for (int i = 0; i < NT; ++i) dstv[tid + i * 256] = srcv[tid + i * 256];
    }
    if (MODE == 1) sstat[tid] = 0.f;

    int wave = tid >> 6, lane = tid & 63;
    int r0 = blockIdx.x * 64 + wave * 16;
    int kg = lane >> 4;
    int cl = lane & 15;

    int arow = r0 + cl;
    int acl = arow < M ? arow : M - 1;
    short8 afrag[4];
    if (MODE == 0) {
        const float* xr = Xf + (size_t)acl * 128;
#pragma unroll
        for (int kk = 0; kk < 4; ++kk) {
            float4 a = *(const float4*)(xr + kk * 32 + kg * 8);
            float4 b = *(const float4*)(xr + kk * 32 + kg * 8 + 4);
            short8 t;
            t[0] = (short)f2bf(a.x); t[1] = (short)f2bf(a.y);
            t[2] = (short)f2bf(a.z); t[3] = (short)f2bf(a.w);
            t[4] = (short)f2bf(b.x); t[5] = (short)f2bf(b.y);
            t[6] = (short)f2bf(b.z); t[7] = (short)f2bf(b.w);
            afrag[kk] = t;
        }
    } else {
#pragma unroll
        for (int kk = 0; kk < 4; ++kk)  // k-range [kk*32, kk*32+32) = slice kk
            afrag[kk] = *(const short8*)(Zrw + ((size_t)kk * NP + acl) * 32 + kg * 8);
    }

    __syncthreads();

    f32x4 acc[NT];
#pragma unroll
    for (int nt = 0; nt < NT; ++nt) {
        acc[nt] = (f32x4){0.f, 0.f, 0.f, 0.f};
        int j = nt * 16 + cl;
        const u16* wrow = Ws + j * 128;
        int sw = (j & 7) << 3;
#pragma unroll
        for (int kk = 0; kk < 4; ++kk) {
            short8 b = *(const short8*)(wrow + ((kk * 32 + kg * 8) ^ sw));
            acc[nt] = __builtin_amdgcn_mfma_f32_16x16x32_bf16(afrag[kk], b, acc[nt], 0, 0, 0);
        }
    }

    int rbase = r0 + kg * 4;
    float dvr[4];
    if (MODE != 1) {
#pragma unroll
        for (int reg = 0; reg < 4; ++reg) {
            int row = rbase + reg;
            dvr[reg] = (row < M) ? dinv[row] : 1.f;
        }
    }

#pragma unroll
    for (int nt = 0; nt < NT; ++nt) {
        int j = nt * 16 + cl;
        float s = 0.f, ss = 0.f;
#pragma unroll
        for (int reg = 0; reg < 4; ++reg) {
            int row = rbase + reg;
            if (row >= M) continue;
            float v = acc[nt][reg];
            size_t idx = ((size_t)(nt >> 1) * NP + row) * 32 + (nt & 1) * 16 + cl;
            if (MODE == 0) {
                v = fmaxf(v + bias[j], 0.f);
                h0b[idx] = f2bf(v);
                hbp[idx] = f2bf(v * dvr[reg]);
            } else if (MODE == 1) {
                float zin = bf2f(Zrw[idx]);
                v = (1.0f - beta_c) * zin + beta_c * v;
                Zrw[idx] = f2bf(v);       // in place; stats use unrounded v
                s += v;
                ss = fmaf(v, v, ss);
            } else {
                outF[(size_t)row * (NT * 16) + j] = v / dvr[reg] + bias[j];
            }
        }
        if (MODE == 1) {
            s  += __shfl_xor(s, 16);  s  += __shfl_xor(s, 32);
            ss += __shfl_xor(ss, 16); ss += __shfl_xor(ss, 32);
            if (kg == 0) {
                atomicAdd(&sstat[j], s);
                atomicAdd(&sstat[128 + j], ss);
            }
        }
    }
    if (MODE == 1) {
        __syncthreads();
        atomicAdd(&stats[tid], sstat[tid]);
    }
}

// ---------------------------------------------------------------------------
// Sparse aggregation v7: 4 slices x 32 feats (64B rows = 1 cache line).
// slice = blockIdx&3. 4 lanes/row x 16B, 16 rows/wave, 64 rows/block.
// Explicit 2-deep software pipeline + packed float2 accumulation.
// ---------------------------------------------------------------------------
#define GATH(S, D0,D1,D2,D3,D4,D5,D6,D7) \
    D0 = *(const uint4*)(hs + (size_t)(S.x & 0xffffu) * 32 + hf * 8); \
    D1 = *(const uint4*)(hs + (size_t)(S.x >> 16)     * 32 + hf * 8); \
    D2 = *(const uint4*)(hs + (size_t)(S.y & 0xffffu) * 32 + hf * 8); \
    D3 = *(const uint4*)(hs + (size_t)(S.y >> 16)     * 32 + hf * 8); \
    D4 = *(const uint4*)(hs + (size_t)(S.z & 0xffffu) * 32 + hf * 8); \
    D5 = *(const uint4*)(hs + (size_t)(S.z >> 16)     * 32 + hf * 8); \
    D6 = *(const uint4*)(hs + (size_t)(S.w & 0xffffu) * 32 + hf * 8); \
    D7 = *(const uint4*)(hs + (size_t)(S.w >> 16)     * 32 + hf * 8);

#define ACC4(U) \
    c0 += (f32x2){blo(U.x), bhi(U.x)}; \
    c1 += (f32x2){blo(U.y), bhi(U.y)}; \
    c2 += (f32x2){blo(U.z), bhi(U.z)}; \
    c3 += (f32x2){blo(U.w), bhi(U.w)};

#define ACC8(U0,U1,U2,U3,U4,U5,U6,U7) \
    ACC4(U0) ACC4(U1) ACC4(U2) ACC4(U3) ACC4(U4) ACC4(U5) ACC4(U6) ACC4(U7)

__global__ __launch_bounds__(256) void k_aggregate(const u16* __restrict__ hbp, const u16* __restrict__ h0b,
                                                   const int* __restrict__ rowptr, const u16* __restrict__ ssrc,
                                                   const float* __restrict__ dinv, const int* __restrict__ perm,
                                                   u16* __restrict__ Zb) {
    int slice = blockIdx.x & 3;
    int wave = threadIdx.x >> 6, lane = threadIdx.x & 63;
    int rg = lane >> 2, hf = lane & 3;
    int idx = (blockIdx.x >> 2) * 64 + wave * 16 + rg;
    if (idx >= N_NODES) return;
    int v = perm[idx];
    const u16* hs = hbp + (size_t)slice * NP * 32;
    int beg = rowptr[v];
    int nit = (rowptr[v + 1] - beg) >> 3;

    f32x2 c0, c1, c2, c3;
    {   // self-loop
        uint4 u = *(const uint4*)(hs + (size_t)v * 32 + hf * 8);
        c0 = (f32x2){blo(u.x), bhi(u.x)};
        c1 = (f32x2){blo(u.y), bhi(u.y)};
        c2 = (f32x2){blo(u.z), bhi(u.z)};
        c3 = (f32x2){blo(u.w), bhi(u.w)};
    }
    const uint4* sv = (const uint4*)(ssrc + beg);   // beg is multiple of 8
    if (nit > 0) {
        uint4 A0, A1, A2, A3, A4, A5, A6, A7;
        uint4 B0, B1, B2, B3, B4, B5, B6, B7;
        uint4 S = sv[0];
        GATH(S, A0, A1, A2, A3, A4, A5, A6, A7)
        int it = 0;
        for (; it + 2 <= nit; it += 2) {
            uint4 T = sv[it + 1];
            GATH(T, B0, B1, B2, B3, B4, B5, B6, B7)
            ACC8(A0, A1, A2, A3, A4, A5, A6, A7)
            if (it + 2 < nit) {
                S = sv[it + 2];
                GATH(S, A0, A1, A2, A3, A4, A5, A6, A7)
            }
            ACC8(B0, B1, B2, B3, B4, B5, B6, B7)
        }
        if (it < nit) {   // odd tail: bank A holds the last gathered vector
            ACC8(A0, A1, A2, A3, A4, A5, A6, A7)
        }
    }

    float dv = dinv[v] * (1.0f - ALPHA_C);
    size_t oidx = ((size_t)slice * NP + v) * 32 + hf * 8;
    uint4 uh = *(const uint4*)(h0b + oidx);
    f32x2 z0 = dv * c0 + ALPHA_C * (f32x2){blo(uh.x), bhi(uh.x)};
    f32x2 z1 = dv * c1 + ALPHA_C * (f32x2){blo(uh.y), bhi(uh.y)};
    f32x2 z2 = dv * c2 + ALPHA_C * (f32x2){blo(uh.z), bhi(uh.z)};
    f32x2 z3 = dv * c3 + ALPHA_C * (f32x2){blo(uh.w), bhi(uh.w)};
    uint4 o;
    o.x = (unsigned)f2bf(z0.x) | ((unsigned)f2bf(z0.y) << 16);
    o.y = (unsigned)f2bf(z1.x) | ((unsigned)f2bf(z1.y) << 16);
    o.z = (unsigned)f2bf(z2.x) | ((unsigned)f2bf(z2.y) << 16);
    o.w = (unsigned)f2bf(z3.x) | ((unsigned)f2bf(z3.y) << 16);
    *(uint4*)(Zb + oidx) = o;
}

// ---------------------------------------------------------------------------
// BN finalize + apply + relu + dinv-prescale. Zb bf16 slice-major -> hbp bf16.
// 8 bf16 (16B) in / 16B out per thread.
// ---------------------------------------------------------------------------
__global__ __launch_bounds__(256) void k_bn_relu(const u16* __restrict__ Zb, const float* __restrict__ stats,
                                                 const float* __restrict__ gamma, const float* __restrict__ betap,
                                                 const float* __restrict__ dinv, u16* __restrict__ hbp) {
    __shared__ float ssc[128], ssh[128];
    int t = threadIdx.x;
    if (t < 128) {
        float mean = stats[t] * (1.0f / N_NODES);
        float var = stats[128 + t] * (1.0f / N_NODES) - mean * mean;
        float istd = rsqrtf(var + BN_EPS);
        float sc = gamma[t] * istd;
        ssc[t] = sc;
        ssh[t] = betap[t] - mean * sc;
    }
    __syncthreads();
    int e8 = blockIdx.x * 256 + t;      // N*16 chunks of 8 elems
    if (e8 >= N_NODES * 16) return;
    int slice = e8 / (N_NODES * 4);
    int rem = e8 - slice * (N_NODES * 4);
    int row = rem >> 2;
    int q = rem & 3;
    size_t addr = ((size_t)slice * NP + row) * 32 + q * 8;
    int j0 = slice * 32 + q * 8;
    float dv = dinv[row];
    uint4 z = *(const uint4*)(Zb + addr);
    float r0 = fmaxf(fmaf(blo(z.x), ssc[j0 + 0], ssh[j0 + 0]), 0.f) * dv;
    float r1 = fmaxf(fmaf(bhi(z.x), ssc[j0 + 1], ssh[j0 + 1]), 0.f) * dv;
    float r2 = fmaxf(fmaf(blo(z.y), ssc[j0 + 2], ssh[j0 + 2]), 0.f) * dv;
    float r3 = fmaxf(fmaf(bhi(z.y), ssc[j0 + 3], ssh[j0 + 3]), 0.f) * dv;
    float r4 = fmaxf(fmaf(blo(z.z), ssc[j0 + 4], ssh[j0 + 4]), 0.f) * dv;
    float r5 = fmaxf(fmaf(bhi(z.z), ssc[j0 + 5], ssh[j0 + 5]), 0.f) * dv;
    float r6 = fmaxf(fmaf(blo(z.w), ssc[j0 + 6], ssh[j0 + 6]), 0.f) * dv;
    float r7 = fmaxf(fmaf(bhi(z.w), ssc[j0 + 7], ssh[j0 + 7]), 0.f) * dv;
    uint4 o;
    o.x = (unsigned)f2bf(r0) | ((unsigned)f2bf(r1) << 16);
    o.y = (unsigned)f2bf(r2) | ((unsigned)f2bf(r3) << 16);
    o.z = (unsigned)f2bf(r4) | ((unsigned)f2bf(r5) << 16);
    o.w = (unsigned)f2bf(r6) | ((unsigned)f2bf(r7) << 16);
    *(uint4*)(hbp + addr) = o;
}

// ---------------------------------------------------------------------------

extern "C" void kernel_launch(void* const* d_in, const int* in_sizes, int n_in,
                              void* d_out, int out_size, void* d_ws, size_t ws_size,
                              hipStream_t stream) {
    const float* x      = (const float*)d_in[0];
    const int*   ei     = (const int*)d_in[1];
    const float* lin0_w = (const float*)d_in[2];
    const float* lin0_b = (const float*)d_in[3];
    const float* lin1_w = (const float*)d_in[4];
    const float* lin1_b = (const float*)d_in[5];
    const float* conv_w = (const float*)d_in[6];
    const float* bn_g   = (const float*)d_in[7];
    const float* bn_b   = (const float*)d_in[8];
    const int* e_src = ei;
    const int* e_dst = ei + N_EDGES;

    char* p = (char*)d_ws;
    auto alloc = [&](size_t bytes) -> void* {
        void* r = (void*)p;
        p += (bytes + 255) & ~(size_t)255;
        return r;
    };
    int*   cnt    = (int*)alloc((size_t)N_NODES * 4);
    int*   rowptr = (int*)alloc((size_t)(N_NODES + 1) * 4);
    int*   fill   = (int*)alloc((size_t)N_NODES * 4);
    float* dinv   = (float*)alloc((size_t)N_NODES * 4);
    u16*   ssrc   = (u16*)alloc((size_t)SSRC_CAP * 2);
    int*   bsum   = (int*)alloc(64 * 4);
    int*   perm   = (int*)alloc((size_t)N_NODES * 4);
    u16*   h0b    = (u16*)alloc((size_t)4 * NP * 32 * 2);
    u16*   Zb     = (u16*)alloc((size_t)4 * NP * 32 * 2);
    u16*   hbp    = (u16*)alloc((size_t)4 * NP * 32 * 2);
    u16*   wtb    = (u16*)alloc((size_t)(131072 + 16384 + 8192) * 2);
    float* stats  = (float*)alloc((size_t)NLAYERS * 256 * 4);

    const int nblk = (N_NODES + 255) / 256;
    const int eblk = (N_EDGES + 255) / 256;
    const int gblk = (N_NODES + 63) / 64;            // 782
    const int ablk = ((N_NODES + 63) / 64) * 4;      // 3128
    const int bnblk = N_NODES * 16 / 256;            // 3125
    const int cpblk = CB_COUNT + CB_CONVW + CB_FILL; // 4320

    k_init<<<nblk, 256, 0, stream>>>(cnt, fill, stats, hbp);
    k_countprep<<<cpblk, 256, 0, stream>>>(e_dst, cnt, conv_w, lin0_w, lin1_w, wtb, ssrc);
    k_graphA<<<49, 1024, 0, stream>>>(cnt, dinv, perm, rowptr, bsum);
    k_scan_top<<<1, 64, 0, stream>>>(bsum);
    k_scan_add<<<196, 256, 0, stream>>>(rowptr, bsum);
    k_scatter<<<eblk, 256, 0, stream>>>(e_src, e_dst, rowptr, fill, ssrc);

    // input projection: h0b + hbp = relu(x @ lin0_w.T + b)   (reads x f32 directly)
    k_gemm_mfma<8, 0><<<gblk, 256, 0, stream>>>(x, nullptr, wtb + 131072, lin0_b, h0b, hbp, nullptr, nullptr, dinv, 0.f, N_NODES);

    for (int i = 0; i < NLAYERS; ++i) {
        k_aggregate<<<ablk, 256, 0, stream>>>(hbp, h0b, rowptr, ssrc, dinv, perm, Zb);
        float beta = (float)log(0.5 / (double)(i + 1) + 1.0);
        k_gemm_mfma<8, 1><<<gblk, 256, 0, stream>>>(nullptr, Zb, wtb + (size_t)i * 16384, nullptr, nullptr, nullptr, nullptr, stats + (size_t)i * 256, nullptr, beta, N_NODES);
        k_bn_relu<<<bnblk, 256, 0, stream>>>(Zb, stats + (size_t)i * 256, bn_g + i * 128, bn_b + i * 128, dinv, hbp);
    }

    // output projection
    k_gemm_mfma<4, 2><<<gblk, 256, 0, stream>>>(nullptr, hbp, wtb + 147456, lin1_b, nullptr, nullptr, (float*)d_out, nullptr, dinv, 0.f, N_NODES);
}

// Round 11
// 738.597 us; speedup vs baseline: 1.4746x; 1.0197x over previous
//
#include <hip/hip_runtime.h>
#include <hip/hip_bf16.h>
#include <math.h>

#define N_NODES 50000
#define NP      (N_NODES + 1)        // slice row stride (row N = zero dummy)
#define N_EDGES 800000
#define SSRC_CAP (N_EDGES + 8 * N_NODES)   // padded CSR capacity (1.2M)
#define NLAYERS 8
#define ALPHA_C 0.1f
#define BN_EPS  1e-5f

typedef unsigned short u16;
typedef __attribute__((ext_vector_type(8))) short short8;
typedef __attribute__((ext_vector_type(4))) float f32x4;
typedef __attribute__((ext_vector_type(2))) float f32x2;

static __device__ __forceinline__ u16 f2bf(float f) {
    unsigned u = __float_as_uint(f);
    unsigned r = (u + 0x7fffu + ((u >> 16) & 1u)) >> 16;
    return (u16)r;
}
static __device__ __forceinline__ float bf2f(u16 b) {
    return __uint_as_float((unsigned)b << 16);
}
static __device__ __forceinline__ float blo(unsigned w) { return __uint_as_float(w << 16); }
static __device__ __forceinline__ float bhi(unsigned w) { return __uint_as_float(w & 0xffff0000u); }

// ---------------------------------------------------------------------------
// init: zero cnt/fill/stats + the dummy rows (row N) of hbp in all 4 slices
// ---------------------------------------------------------------------------
__global__ __launch_bounds__(256) void k_init(int* cnt, int* fill, float* stats, u16* hbp) {
    int i = blockIdx.x * 256 + threadIdx.x;
    if (i < N_NODES) { cnt[i] = 0; fill[i] = 0; }
    if (i < NLAYERS * 256) stats[i] = 0.0f;
    if (i < 128) {  // 4 slices x 32 feats of dummy row N
        int s = i >> 5, c = i & 31;
        hbp[((size_t)s * NP + N_NODES) * 32 + c] = 0;
    }
}

// ---------------------------------------------------------------------------
// fused: degree count | convw | ssrc pad-fill   (independent works)
// ---------------------------------------------------------------------------
#define CB_COUNT 3125            // ceil(E/256)
#define CB_CONVW 608             // ceil(155648/256)
#define CB_FILL  587             // ceil(SSRC_CAP/8/256)

__global__ __launch_bounds__(256) void k_countprep(const int* __restrict__ dst, int* cnt,
                                                   const float* __restrict__ conv_w,
                                                   const float* __restrict__ lin0_w,
                                                   const float* __restrict__ lin1_w,
                                                   u16* __restrict__ wtb,
                                                   u16* __restrict__ ssrc) {
    int b = blockIdx.x;
    if (b < CB_COUNT) {
        int e = b * 256 + threadIdx.x;
        if (e < N_EDGES) atomicAdd(&cnt[dst[e]], 1);
    } else if (b < CB_COUNT + CB_CONVW) {
        int t = (b - CB_COUNT) * 256 + threadIdx.x;
        if (t < 131072) {                       // conv: B[j][k] = conv_w[i][k][j], swizzled
            int j = (t >> 7) & 127, k = t & 127;
            int i = t >> 14;
            float v = conv_w[(i << 14) + (k << 7) + j];
            wtb[(t & ~127) | (k ^ ((j & 7) << 3))] = f2bf(v);
        } else if (t < 131072 + 16384) {        // lin0_w [128][128]
            int u = t - 131072;
            int j = u >> 7, k = u & 127;
            wtb[131072 + ((u & ~127) | (k ^ ((j & 7) << 3)))] = f2bf(lin0_w[u]);
        } else if (t < 131072 + 16384 + 8192) { // lin1_w [64][128]
            int u = t - 147456;
            int j = u >> 7, k = u & 127;
            wtb[147456 + ((u & ~127) | (k ^ ((j & 7) << 3)))] = f2bf(lin1_w[u]);
        }
    } else {
        // fill ssrc with dummy index N (pattern 8 x u16)
        size_t q = ((size_t)(b - CB_COUNT - CB_CONVW) * 256 + threadIdx.x);
        unsigned pat = (unsigned)N_NODES | ((unsigned)N_NODES << 16);
        if (q * 8 < SSRC_CAP) {
            uint4 o = make_uint4(pat, pat, pat, pat);
            *(uint4*)(ssrc + q * 8) = o;
        }
    }
}

// ---------------------------------------------------------------------------
// fused graph pass: dinv + block-local(128) degree sort + padded-count scan
// grid 49 x 1024
// ---------------------------------------------------------------------------
__global__ __launch_bounds__(1024) void k_graphA(const int* __restrict__ cnt, float* __restrict__ dinv,
                                                 int* __restrict__ perm,
                                                 int* __restrict__ rowptr, int* __restrict__ bsum) {
    __shared__ int tmp[1024];
    int t = threadIdx.x;
    int i = blockIdx.x * 1024 + t;
    int deg = (i < N_NODES) ? cnt[i] : 0;
    if (i < N_NODES) dinv[i] = rsqrtf((float)(deg + 1));
    // --- local degree sort over 128-row groups ---
    tmp[t] = (i < N_NODES) ? deg : 0x7fffffff;
    __syncthreads();
    {
        int g = t >> 7, tl = t & 127;
        int k = tmp[t];
        int r = 0;
#pragma unroll 8
        for (int j = 0; j < 128; ++j) {
            int kj = tmp[(g << 7) + j];
            r += (kj < k) || (kj == k && j < tl);
        }
        if (i < N_NODES) perm[blockIdx.x * 1024 + (g << 7) + r] = i;
    }
    __syncthreads();
    // --- scan of padded degrees ---
    int vpad = (i < N_NODES) ? ((deg + 7) & ~7) : 0;
    tmp[t] = vpad;
    __syncthreads();
    for (int off = 1; off < 1024; off <<= 1) {
        int y = (t >= off) ? tmp[t - off] : 0;
        __syncthreads();
        tmp[t] += y;
        __syncthreads();
    }
    if (i < N_NODES) rowptr[i] = tmp[t] - vpad;
    if (t == 1023) bsum[blockIdx.x] = tmp[t];
}

__global__ void k_scan_top(int* bsum) {
    __shared__ int tmp[64];
    int t = threadIdx.x;
    int v = (t < 49) ? bsum[t] : 0;
    tmp[t] = v;
    __syncthreads();
    for (int off = 1; off < 64; off <<= 1) {
        int y = (t >= off) ? tmp[t - off] : 0;
        __syncthreads();
        tmp[t] += y;
        __syncthreads();
    }
    if (t < 49) bsum[t] = tmp[t] - v;
    if (t == 48) bsum[63] = tmp[48];  // grand total (padded)
}

__global__ __launch_bounds__(256) void k_scan_add(int* __restrict__ rowptr, const int* __restrict__ bsum) {
    int i = blockIdx.x * 256 + threadIdx.x;
    if (i < N_NODES) rowptr[i] += bsum[i >> 10];
    if (i == 0) rowptr[N_NODES] = bsum[63];
}

__global__ __launch_bounds__(256) void k_scatter(const int* __restrict__ src, const int* __restrict__ dst,
                                                 const int* __restrict__ rowptr, int* fill,
                                                 u16* __restrict__ ssrc) {
    int e = blockIdx.x * 256 + threadIdx.x;
    if (e < N_EDGES) {
        int d = dst[e];
        int pos = rowptr[d] + atomicAdd(&fill[d], 1);
        ssrc[pos] = (u16)src[e];
    }
}

// ---------------------------------------------------------------------------
// MFMA GEMM: 64 rows/block, NT*16 cols/block, NJB j-blocks (split-j for
// block-latency reduction: 2x blocks, half LDS/MFMA/epilogue per block).
// blockIdx: jh = blockIdx % NJB, rowtile = blockIdx / NJB.
// MODE 0: A=Xf (f32 row-major, cvt); v=relu(acc+bias); h0b/hbp (slice-major)
// MODE 1: A=Zin (bf16 slice-major); v=(1-beta)*Zin + beta*acc; Zout=bf16(v)
//         (separate buffer — split-j makes in-place a race); BN stats
// MODE 2: A=Zin(=hbp); outF[row*64+j] = acc/dinv[row] + bias[j]
// ---------------------------------------------------------------------------
template<int NT, int MODE, int NJB>
__global__ __launch_bounds__(256) void k_gemm_mfma(const float* __restrict__ Xf,
                                                   const u16* __restrict__ Zin,
                                                   u16* __restrict__ Zout,
                                                   const u16* __restrict__ Wg,
                                                   const float* __restrict__ bias,
                                                   u16* __restrict__ h0b,
                                                   u16* __restrict__ hbp,
                                                   float* __restrict__ outF,
                                                   float* __restrict__ stats,
                                                   const float* __restrict__ dinv,
                                                   float beta_c, int M) {
    __shared__ u16 Ws[NT * 16 * 128];
    __shared__ float sstat[2 * NT * 16];
    int tid = threadIdx.x;
    int jh = (NJB > 1) ? (blockIdx.x % NJB) : 0;
    int rowtile = (NJB > 1) ? (blockIdx.x / NJB) : blockIdx.x;
    int j0 = jh * NT * 16;

    {
        const float4* srcv = (const float4*)Wg + (size_t)j0 * 16;  // j0*128 elems / 8
        float4* dstv = (float4*)Ws;
#pragma unroll
        for (int i = 0; i < NT; ++i) dstv[tid + i * 256] = srcv[tid + i * 256];
    }
    if (MODE == 1 && tid < 2 * NT * 16) sstat[tid] = 0.f;

    int wave = tid >> 6, lane = tid & 63;
    int r0 = rowtile * 64 + wave * 16;
    int kg = lane >> 4;
    int cl = lane & 15;

    int arow = r0 + cl;
    int acl = arow < M ? arow : M - 1;
    short8 afrag[4];
    if (MODE == 0) {
        const float* xr = Xf + (size_t)acl * 128;
#pragma unroll
        for (int kk = 0; kk < 4; ++kk) {
            float4 a = *(const float4*)(xr + kk * 32 + kg * 8);
            float4 b = *(const float4*)(xr + kk * 32 + kg * 8 + 4);
            short8 t;
            t[0] = (short)f2bf(a.x); t[1] = (short)f2bf(a.y);
            t[2] = (short)f2bf(a.z); t[3] = (short)f2bf(a.w);
            t[4] = (short)f2bf(b.x); t[5] = (short)f2bf(b.y);
            t[6] = (short)f2bf(b.z); t[7] = (short)f2bf(b.w);
            afrag[kk] = t;
        }
    } else {
#pragma unroll
        for (int kk = 0; kk < 4; ++kk)  // k-range [kk*32, kk*32+32) = slice kk
            afrag[kk] = *(const short8*)(Zin + ((size_t)kk * NP + acl) * 32 + kg * 8);
    }

    __syncthreads();

    f32x4 acc[NT];
#pragma unroll
    for (int nt = 0; nt < NT; ++nt) {
        acc[nt] = (f32x4){0.f, 0.f, 0.f, 0.f};
        int lj = nt * 16 + cl;               // local col in [0, NT*16)
        const u16* wrow = Ws + lj * 128;
        int sw = (lj & 7) << 3;              // (global j & 7) == (lj & 7) since j0 % 64 == 0
#pragma unroll
        for (int kk = 0; kk < 4; ++kk) {
            short8 b = *(const short8*)(wrow + ((kk * 32 + kg * 8) ^ sw));
            acc[nt] = __builtin_amdgcn_mfma_f32_16x16x32_bf16(afrag[kk], b, acc[nt], 0, 0, 0);
        }
    }

    int rbase = r0 + kg * 4;
    float dvr[4];
    if (MODE != 1) {
#pragma unroll
        for (int reg = 0; reg < 4; ++reg) {
            int row = rbase + reg;
            dvr[reg] = (row < M) ? dinv[row] : 1.f;
        }
    }

#pragma unroll
    for (int nt = 0; nt < NT; ++nt) {
        int j = j0 + nt * 16 + cl;           // global col
        int sl = (j0 + nt * 16) >> 5;        // slice
        int so = ((j0 + nt * 16) & 31) + cl; // within-slice col
        float s = 0.f, ss = 0.f;
#pragma unroll
        for (int reg = 0; reg < 4; ++reg) {
            int row = rbase + reg;
            if (row >= M) continue;
            float v = acc[nt][reg];
            size_t idx = ((size_t)sl * NP + row) * 32 + so;
            if (MODE == 0) {
                v = fmaxf(v + bias[j], 0.f);
                h0b[idx] = f2bf(v);
                hbp[idx] = f2bf(v * dvr[reg]);
            } else if (MODE == 1) {
                float zin = bf2f(Zin[idx]);
                v = (1.0f - beta_c) * zin + beta_c * v;
                Zout[idx] = f2bf(v);         // separate buffer; stats use unrounded v
                s += v;
                ss = fmaf(v, v, ss);
            } else {
                outF[(size_t)row * (NT * 16) + j] = v / dvr[reg] + bias[j];
            }
        }
        if (MODE == 1) {
            s  += __shfl_xor(s, 16);  s  += __shfl_xor(s, 32);
            ss += __shfl_xor(ss, 16); ss += __shfl_xor(ss, 32);
            if (kg == 0) {
                atomicAdd(&sstat[nt * 16 + cl], s);
                atomicAdd(&sstat[NT * 16 + nt * 16 + cl], ss);
            }
        }
    }
    if (MODE == 1) {
        __syncthreads();
        if (tid < NT * 16)
            atomicAdd(&stats[j0 + tid], sstat[tid]);
        else if (tid < 2 * NT * 16)
            atomicAdd(&stats[128 + j0 + tid - NT * 16], sstat[tid]);
    }
}

// ---------------------------------------------------------------------------
// Sparse aggregation v7: 4 slices x 32 feats (64B rows = 1 cache line).
// slice = blockIdx&3. 4 lanes/row x 16B, 16 rows/wave, 64 rows/block.
// Explicit 2-deep software pipeline + packed float2 accumulation.
// ---------------------------------------------------------------------------
#define GATH(S, D0,D1,D2,D3,D4,D5,D6,D7) \
    D0 = *(const uint4*)(hs + (size_t)(S.x & 0xffffu) * 32 + hf * 8); \
    D1 = *(const uint4*)(hs + (size_t)(S.x >> 16)     * 32 + hf * 8); \
    D2 = *(const uint4*)(hs + (size_t)(S.y & 0xffffu) * 32 + hf * 8); \
    D3 = *(const uint4*)(hs + (size_t)(S.y >> 16)     * 32 + hf * 8); \
    D4 = *(const uint4*)(hs + (size_t)(S.z & 0xffffu) * 32 + hf * 8); \
    D5 = *(const uint4*)(hs + (size_t)(S.z >> 16)     * 32 + hf * 8); \
    D6 = *(const uint4*)(hs + (size_t)(S.w & 0xffffu) * 32 + hf * 8); \
    D7 = *(const uint4*)(hs + (size_t)(S.w >> 16)     * 32 + hf * 8);

#define ACC4(U) \
    c0 += (f32x2){blo(U.x), bhi(U.x)}; \
    c1 += (f32x2){blo(U.y), bhi(U.y)}; \
    c2 += (f32x2){blo(U.z), bhi(U.z)}; \
    c3 += (f32x2){blo(U.w), bhi(U.w)};

#define ACC8(U0,U1,U2,U3,U4,U5,U6,U7) \
    ACC4(U0) ACC4(U1) ACC4(U2) ACC4(U3) ACC4(U4) ACC4(U5) ACC4(U6) ACC4(U7)

__global__ __launch_bounds__(256) void k_aggregate(const u16* __restrict__ hbp, const u16* __restrict__ h0b,
                                                   const int* __restrict__ rowptr, const u16* __restrict__ ssrc,
                                                   const float* __restrict__ dinv, const int* __restrict__ perm,
                                                   u16* __restrict__ Zb) {
    int slice = blockIdx.x & 3;
    int wave = threadIdx.x >> 6, lane = threadIdx.x & 63;
    int rg = lane >> 2, hf = lane & 3;
    int idx = (blockIdx.x >> 2) * 64 + wave * 16 + rg;
    if (idx >= N_NODES) return;
    int v = perm[idx];
    const u16* hs = hbp + (size_t)slice * NP * 32;
    int beg = rowptr[v];
    int nit = (rowptr[v + 1] - beg) >> 3;

    f32x2 c0, c1, c2, c3;
    {   // self-loop
        uint4 u = *(const uint4*)(hs + (size_t)v * 32 + hf * 8);
        c0 = (f32x2){blo(u.x), bhi(u.x)};
        c1 = (f32x2){blo(u.y), bhi(u.y)};
        c2 = (f32x2){blo(u.z), bhi(u.z)};
        c3 = (f32x2){blo(u.w), bhi(u.w)};
    }
    const uint4* sv = (const uint4*)(ssrc + beg);   // beg is multiple of 8
    if (nit > 0) {
        uint4 A0, A1, A2, A3, A4, A5, A6, A7;
        uint4 B0, B1, B2, B3, B4, B5, B6, B7;
        uint4 S = sv[0];
        GATH(S, A0, A1, A2, A3, A4, A5, A6, A7)
        int it = 0;
        for (; it + 2 <= nit; it += 2) {
            uint4 T = sv[it + 1];
            GATH(T, B0, B1, B2, B3, B4, B5, B6, B7)
            ACC8(A0, A1, A2, A3, A4, A5, A6, A7)
            if (it + 2 < nit) {
                S = sv[it + 2];
                GATH(S, A0, A1, A2, A3, A4, A5, A6, A7)
            }
            ACC8(B0, B1, B2, B3, B4, B5, B6, B7)
        }
        if (it < nit) {   // odd tail: bank A holds the last gathered vector
            ACC8(A0, A1, A2, A3, A4, A5, A6, A7)
        }
    }

    float dv = dinv[v] * (1.0f - ALPHA_C);
    size_t oidx = ((size_t)slice * NP + v) * 32 + hf * 8;
    uint4 uh = *(const uint4*)(h0b + oidx);
    f32x2 z0 = dv * c0 + ALPHA_C * (f32x2){blo(uh.x), bhi(uh.x)};
    f32x2 z1 = dv * c1 + ALPHA_C * (f32x2){blo(uh.y), bhi(uh.y)};
    f32x2 z2 = dv * c2 + ALPHA_C * (f32x2){blo(uh.z), bhi(uh.z)};
    f32x2 z3 = dv * c3 + ALPHA_C * (f32x2){blo(uh.w), bhi(uh.w)};
    uint4 o;
    o.x = (unsigned)f2bf(z0.x) | ((unsigned)f2bf(z0.y) << 16);
    o.y = (unsigned)f2bf(z1.x) | ((unsigned)f2bf(z1.y) << 16);
    o.z = (unsigned)f2bf(z2.x) | ((unsigned)f2bf(z2.y) << 16);
    o.w = (unsigned)f2bf(z3.x) | ((unsigned)f2bf(z3.y) << 16);
    *(uint4*)(Zb + oidx) = o;
}

// ---------------------------------------------------------------------------
// BN finalize + apply + relu + dinv-prescale. Zbn bf16 slice-major -> hbp bf16.
// 8 bf16 (16B) in / 16B out per thread.
// ---------------------------------------------------------------------------
__global__ __launch_bounds__(256) void k_bn_relu(const u16* __restrict__ Zb, const float* __restrict__ stats,
                                                 const float* __restrict__ gamma, const float* __restrict__ betap,
                                                 const float* __restrict__ dinv, u16* __restrict__ hbp) {
    __shared__ float ssc[128], ssh[128];
    int t = threadIdx.x;
    if (t < 128) {
        float mean = stats[t] * (1.0f / N_NODES);
        float var = stats[128 + t] * (1.0f / N_NODES) - mean * mean;
        float istd = rsqrtf(var + BN_EPS);
        float sc = gamma[t] * istd;
        ssc[t] = sc;
        ssh[t] = betap[t] - mean * sc;
    }
    __syncthreads();
    int e8 = blockIdx.x * 256 + t;      // N*16 chunks of 8 elems
    if (e8 >= N_NODES * 16) return;
    int slice = e8 / (N_NODES * 4);
    int rem = e8 - slice * (N_NODES * 4);
    int row = rem >> 2;
    int q = rem & 3;
    size_t addr = ((size_t)slice * NP + row) * 32 + q * 8;
    int j0 = slice * 32 + q * 8;
    float dv = dinv[row];
    uint4 z = *(const uint4*)(Zb + addr);
    float r0 = fmaxf(fmaf(blo(z.x), ssc[j0 + 0], ssh[j0 + 0]), 0.f) * dv;
    float r1 = fmaxf(fmaf(bhi(z.x), ssc[j0 + 1], ssh[j0 + 1]), 0.f) * dv;
    float r2 = fmaxf(fmaf(blo(z.y), ssc[j0 + 2], ssh[j0 + 2]), 0.f) * dv;
    float r3 = fmaxf(fmaf(bhi(z.y), ssc[j0 + 3], ssh[j0 + 3]), 0.f) * dv;
    float r4 = fmaxf(fmaf(blo(z.z), ssc[j0 + 4], ssh[j0 + 4]), 0.f) * dv;
    float r5 = fmaxf(fmaf(bhi(z.z), ssc[j0 + 5], ssh[j0 + 5]), 0.f) * dv;
    float r6 = fmaxf(fmaf(blo(z.w), ssc[j0 + 6], ssh[j0 + 6]), 0.f) * dv;
    float r7 = fmaxf(fmaf(bhi(z.w), ssc[j0 + 7], ssh[j0 + 7]), 0.f) * dv;
    uint4 o;
    o.x = (unsigned)f2bf(r0) | ((unsigned)f2bf(r1) << 16);
    o.y = (unsigned)f2bf(r2) | ((unsigned)f2bf(r3) << 16);
    o.z = (unsigned)f2bf(r4) | ((unsigned)f2bf(r5) << 16);
    o.w = (unsigned)f2bf(r6) | ((unsigned)f2bf(r7) << 16);
    *(uint4*)(hbp + addr) = o;
}

// ---------------------------------------------------------------------------

extern "C" void kernel_launch(void* const* d_in, const int* in_sizes, int n_in,
                              void* d_out, int out_size, void* d_ws, size_t ws_size,
                              hipStream_t stream) {
    const float* x      = (const float*)d_in[0];
    const int*   ei     = (const int*)d_in[1];
    const float* lin0_w = (const float*)d_in[2];
    const float* lin0_b = (const float*)d_in[3];
    const float* lin1_w = (const float*)d_in[4];
    const float* lin1_b = (const float*)d_in[5];
    const float* conv_w = (const float*)d_in[6];
    const float* bn_g   = (const float*)d_in[7];
    const float* bn_b   = (const float*)d_in[8];
    const int* e_src = ei;
    const int* e_dst = ei + N_EDGES;

    char* p = (char*)d_ws;
    auto alloc = [&](size_t bytes) -> void* {
        void* r = (void*)p;
        p += (bytes + 255) & ~(size_t)255;
        return r;
    };
    int*   cnt    = (int*)alloc((size_t)N_NODES * 4);
    int*   rowptr = (int*)alloc((size_t)(N_NODES + 1) * 4);
    int*   fill   = (int*)alloc((size_t)N_NODES * 4);
    float* dinv   = (float*)alloc((size_t)N_NODES * 4);
    u16*   ssrc   = (u16*)alloc((size_t)SSRC_CAP * 2);
    int*   bsum   = (int*)alloc(64 * 4);
    int*   perm   = (int*)alloc((size_t)N_NODES * 4);
    u16*   h0b    = (u16*)alloc((size_t)4 * NP * 32 * 2);
    u16*   Zagg   = (u16*)alloc((size_t)4 * NP * 32 * 2);   // aggregate output
    u16*   Zbn    = (u16*)alloc((size_t)4 * NP * 32 * 2);   // gemm output (pre-BN)
    u16*   hbp    = (u16*)alloc((size_t)4 * NP * 32 * 2);
    u16*   wtb    = (u16*)alloc((size_t)(131072 + 16384 + 8192) * 2);
    float* stats  = (float*)alloc((size_t)NLAYERS * 256 * 4);

    const int nblk = (N_NODES + 255) / 256;
    const int eblk = (N_EDGES + 255) / 256;
    const int gblk = (N_NODES + 63) / 64;            // 782
    const int ablk = ((N_NODES + 63) / 64) * 4;      // 3128
    const int bnblk = N_NODES * 16 / 256;            // 3125
    const int cpblk = CB_COUNT + CB_CONVW + CB_FILL; // 4320

    k_init<<<nblk, 256, 0, stream>>>(cnt, fill, stats, hbp);
    k_countprep<<<cpblk, 256, 0, stream>>>(e_dst, cnt, conv_w, lin0_w, lin1_w, wtb, ssrc);
    k_graphA<<<49, 1024, 0, stream>>>(cnt, dinv, perm, rowptr, bsum);
    k_scan_top<<<1, 64, 0, stream>>>(bsum);
    k_scan_add<<<196, 256, 0, stream>>>(rowptr, bsum);
    k_scatter<<<eblk, 256, 0, stream>>>(e_src, e_dst, rowptr, fill, ssrc);

    // input projection: h0b + hbp = relu(x @ lin0_w.T + b)   (split-j, NJB=2)
    k_gemm_mfma<4, 0, 2><<<gblk * 2, 256, 0, stream>>>(x, nullptr, nullptr, wtb + 131072, lin0_b, h0b, hbp, nullptr, nullptr, dinv, 0.f, N_NODES);

    for (int i = 0; i < NLAYERS; ++i) {
        k_aggregate<<<ablk, 256, 0, stream>>>(hbp, h0b, rowptr, ssrc, dinv, perm, Zagg);
        float beta = (float)log(0.5 / (double)(i + 1) + 1.0);
        k_gemm_mfma<4, 1, 2><<<gblk * 2, 256, 0, stream>>>(nullptr, Zagg, Zbn, wtb + (size_t)i * 16384, nullptr, nullptr, nullptr, nullptr, stats + (size_t)i * 256, nullptr, beta, N_NODES);
        k_bn_relu<<<bnblk, 256, 0, stream>>>(Zbn, stats + (size_t)i * 256, bn_g + i * 128, bn_b + i * 128, dinv, hbp);
    }

    // output projection (single j-block, NT=4 = 64 cols)
    k_gemm_mfma<4, 2, 1><<<gblk, 256, 0, stream>>>(nullptr, hbp, nullptr, wtb + 147456, lin1_b, nullptr, nullptr, (float*)d_out, nullptr, dinv, 0.f, N_NODES);
}